// Round 2
// baseline (2924.254 us; speedup 1.0000x reference)
//
#include <hip/hip_runtime.h>
#include <hip/hip_bf16.h>
#include <string.h>

typedef __hip_bfloat16 bf16;
typedef short bf16x8 __attribute__((ext_vector_type(8)));
typedef float f32x16 __attribute__((ext_vector_type(16)));

__device__ __forceinline__ float b2f(bf16 v){ return __bfloat162float(v); }
__device__ __forceinline__ bf16  f2b(float v){ return __float2bfloat16(v); }
__device__ __forceinline__ unsigned short f2bu(float v){
  union { bf16 b; unsigned short u; } x; x.b = __float2bfloat16(v); return x.u;
}
__device__ __forceinline__ float ldf(const float* p, size_t i){ return p[i]; }
__device__ __forceinline__ float ldf(const bf16*  p, size_t i){ return b2f(p[i]); }

// bijective XCD-aware block remap (m204): chunk-contiguous per XCD
__device__ __forceinline__ int xcd_swizzle(int lin, int nwg){
  int q = nwg >> 3, r = nwg & 7;
  int x = lin & 7, i = lin >> 3;
  int base = (x < r) ? x * (q + 1) : r * (q + 1) + (x - r) * q;
  return base + i;
}

// load 32 bf16-elems-worth into 4 uint4 regs (converting fp32->bf16 if needed)
template<typename T>
__device__ __forceinline__ void load32(const T* __restrict__ p, bool val, uint4 (&h)[4]){
  if (!val){
    #pragma unroll
    for (int i = 0; i < 4; i++) h[i] = make_uint4(0u,0u,0u,0u);
    return;
  }
  if constexpr (sizeof(T) == 4){
    #pragma unroll
    for (int i = 0; i < 8; i++){
      float4 f = reinterpret_cast<const float4*>(p)[i];
      unsigned int lo = (unsigned int)f2bu(f.x) | ((unsigned int)f2bu(f.y) << 16);
      unsigned int hi = (unsigned int)f2bu(f.z) | ((unsigned int)f2bu(f.w) << 16);
      if ((i & 1) == 0){ h[i>>1].x = lo; h[i>>1].y = hi; }
      else             { h[i>>1].z = lo; h[i>>1].w = hi; }
    }
  } else {
    #pragma unroll
    for (int i = 0; i < 4; i++) h[i] = reinterpret_cast<const uint4*>(p)[i];
  }
}

// ------------------------------------------------------------------
// block-wide (256 thr) mean/var helper. sred must be float[4] shared.
// ------------------------------------------------------------------
__device__ __forceinline__ float2 block_stats256(float x, float* sred){
  float v = x;
  #pragma unroll
  for (int o = 32; o; o >>= 1) v += __shfl_xor(v, o);
  int w = threadIdx.x >> 6;
  if ((threadIdx.x & 63) == 0) sred[w] = v;
  __syncthreads();
  float mean = (sred[0] + sred[1] + sred[2] + sred[3]) * (1.f/256.f);
  __syncthreads();
  float d = x - mean;
  v = d * d;
  #pragma unroll
  for (int o = 32; o; o >>= 1) v += __shfl_xor(v, o);
  if ((threadIdx.x & 63) == 0) sred[w] = v;
  __syncthreads();
  float var = (sred[0] + sred[1] + sred[2] + sred[3]) * (1.f/256.f);
  __syncthreads();
  return make_float2(mean, var);
}

// ---- diagnostics ----
__global__ __launch_bounds__(256) void probe_k(const bf16* __restrict__ buf,
                                               unsigned long long len, float* score){
  __shared__ float sred[4];
  unsigned long long stride = len / 256ull; if (!stride) stride = 1;
  unsigned long long i = (unsigned long long)threadIdx.x * stride;
  if (i >= len) i = len - 1;
  float v = fabsf(b2f(buf[i]));
  #pragma unroll
  for (int o = 32; o; o >>= 1) v = fmaxf(v, __shfl_xor(v, o));
  if ((threadIdx.x & 63) == 0) sred[threadIdx.x >> 6] = v;
  __syncthreads();
  if (threadIdx.x == 0)
    score[0] = fmaxf(fmaxf(sred[0], sred[1]), fmaxf(sred[2], sred[3]));
}

__global__ void verdict_k(const float* score, int nstage, float* out){
  if (threadIdx.x == 0 && blockIdx.x == 0){
    for (int i = 0; i < nstage; i++){
      float s = score[i];
      if (!(s > 1e-8f)){
        float sent = 1000.f + 40.f * i;
        for (int j = 0; j < 64; j++) out[j] = sent;
        return;
      }
    }
  }
}

// ------------------------------------------------------------------
// transpose roi (fp32 NCHW 28x28) -> bf16 NHWC
// ------------------------------------------------------------------
__global__ __launch_bounds__(256) void troi_k(const float* __restrict__ roi,
                                              bf16* __restrict__ o){
  __shared__ float tile[64][65];
  int n = blockIdx.z, c0 = blockIdx.y * 64, p0 = blockIdx.x * 64;
  int a = threadIdx.x & 63, bq = threadIdx.x >> 6;
  #pragma unroll
  for (int cs = bq; cs < 64; cs += 4){
    int p = p0 + a;
    tile[cs][a] = (p < 784) ? roi[((size_t)n*256 + c0 + cs)*784 + p] : 0.f;
  }
  __syncthreads();
  #pragma unroll
  for (int ps = bq; ps < 64; ps += 4){
    int p = p0 + ps;
    if (p < 784) o[((size_t)n*784 + p)*256 + c0 + a] = f2b(tile[a][ps]);
  }
}

// ------------------------------------------------------------------
// weight transpose: w[co][ci][tap] fp32 -> wT[co][tap*256+ci] bf16
// ------------------------------------------------------------------
__global__ __launch_bounds__(256) void wtrans_k(const float* __restrict__ w,
                                                bf16* __restrict__ o){
  int co = blockIdx.x, t = threadIdx.x;
  const float* wp = w + (size_t)co * 2304 + (size_t)t * 9;
  #pragma unroll
  for (int tap = 0; tap < 9; tap++)
    o[(size_t)co * 2304 + tap * 256 + t] = f2b(wp[tap]);
}

// ------------------------------------------------------------------
// MFMA tile compute (128x128 block tile, 4 waves of 64x64, K-step 64)
// LDS row = 64 bf16 = 128B, XOR-swizzled by ((row&7)<<4).
// ------------------------------------------------------------------
__device__ __forceinline__ void mfma_step64(const char* asb, const char* bsb,
                                            int wr, int wc, int lane,
                                            f32x16 (&acc)[2][2]){
  int l31 = lane & 31;
  int lsw = (l31 & 7) << 4;
  int hi  = (lane >> 5) << 4;
  #pragma unroll
  for (int kb = 0; kb < 4; kb++){
    int cb = (kb*32 + hi) ^ lsw;
    bf16x8 a0 = *reinterpret_cast<const bf16x8*>(asb + (wr      + l31)*128 + cb);
    bf16x8 a1 = *reinterpret_cast<const bf16x8*>(asb + (wr + 32 + l31)*128 + cb);
    bf16x8 b0 = *reinterpret_cast<const bf16x8*>(bsb + (wc      + l31)*128 + cb);
    bf16x8 b1 = *reinterpret_cast<const bf16x8*>(bsb + (wc + 32 + l31)*128 + cb);
    acc[0][0] = __builtin_amdgcn_mfma_f32_32x32x16_bf16(a0, b0, acc[0][0], 0, 0, 0);
    acc[0][1] = __builtin_amdgcn_mfma_f32_32x32x16_bf16(a0, b1, acc[0][1], 0, 0, 0);
    acc[1][0] = __builtin_amdgcn_mfma_f32_32x32x16_bf16(a1, b0, acc[1][0], 0, 0, 0);
    acc[1][1] = __builtin_amdgcn_mfma_f32_32x32x16_bf16(a1, b1, acc[1][1], 0, 0, 0);
  }
}

// ------------------------------------------------------------------
// MFMA NT GEMM: C[M,N] = act(A[M,K] @ W[N,K]^T + bias)
// M%128==0, N%128==0, K%64==0.  Double-buffered issue-early pipeline.
// ------------------------------------------------------------------
template<int ACT, typename TA>
__global__ __launch_bounds__(256,2) void gemm_mfma_k(
    const TA* __restrict__ A, const float* __restrict__ W,
    const float* __restrict__ bias, bf16* __restrict__ C,
    int M, int N, int K)
{
  __shared__ __align__(16) unsigned short As[2][8192];
  __shared__ __align__(16) unsigned short Bs[2][8192];
  int t = threadIdx.x;
  int nbx = gridDim.x;
  int lin = blockIdx.y * nbx + blockIdx.x;
  int wg  = xcd_swizzle(lin, nbx * gridDim.y);
  int n0 = (wg % nbx) * 128, m0 = (wg / nbx) * 128;
  int lane = t & 63, wave = t >> 6;
  int wr = (wave >> 1) * 64, wc = (wave & 1) * 64;
  int sr = t >> 1, sk = (t & 1) * 32;
  int swz = (sr & 7) << 4;
  f32x16 acc[2][2];
  #pragma unroll
  for (int i = 0; i < 2; i++)
    #pragma unroll
    for (int j = 0; j < 2; j++)
      #pragma unroll
      for (int r = 0; r < 16; r++) acc[i][j][r] = 0.f;

  const TA*    ap = A + (size_t)(m0 + sr) * K + sk;
  const float* wp = W + (size_t)(n0 + sr) * K + sk;
  uint4 ha[4], hb[4];

  auto commit = [&](int buf){
    char* ar = (char*)As[buf] + sr*128;
    char* br = (char*)Bs[buf] + sr*128;
    #pragma unroll
    for (int i = 0; i < 4; i++){
      *reinterpret_cast<uint4*>(ar + ((sk*2 + i*16) ^ swz)) = ha[i];
      *reinterpret_cast<uint4*>(br + ((sk*2 + i*16) ^ swz)) = hb[i];
    }
  };

  int NIT = K >> 6;
  load32(ap, true, ha);
  load32(wp, true, hb);
  commit(0);
  __syncthreads();
  #pragma unroll 1
  for (int it = 0; it < NIT; ++it){
    if (it + 1 < NIT){
      load32(ap + (size_t)(it+1)*64, true, ha);
      load32(wp + (size_t)(it+1)*64, true, hb);
    }
    mfma_step64((const char*)As[it&1], (const char*)Bs[it&1], wr, wc, lane, acc);
    __syncthreads();
    if (it + 1 < NIT) commit((it+1)&1);
    __syncthreads();
  }

  int l31 = lane & 31;
  int rbase = m0 + wr + ((lane >> 5) << 2);
  #pragma unroll
  for (int j = 0; j < 2; j++){
    int n = n0 + wc + j*32 + l31;
    float bv = bias ? bias[n] : 0.f;
    #pragma unroll
    for (int i = 0; i < 2; i++){
      #pragma unroll
      for (int r = 0; r < 16; r++){
        int row = rbase + i*32 + (r & 3) + ((r >> 2) << 3);
        float v = acc[i][j][r] + bv;
        if (ACT == 1) v = fmaxf(v, 0.f);
        if (ACT == 2) v = v > 0.f ? v : (__expf(v) - 1.f);
        C[(size_t)row * N + n] = f2b(v);
      }
    }
  }
}

// ------------------------------------------------------------------
// MFMA 3x3 conv, Cin=Cout=256, pad 1, NHWC bf16 in/out, batch=128.
// Implicit GEMM: rows = global position (n*HWo+p), cols = co, K=2304.
// Double-buffered issue-early pipeline (36 K-steps of 64).
// RES_MODE: 0 none, 1 bf16 NHWC, 2 fp32 NCHW.
// ------------------------------------------------------------------
template<int Ho,int Wo,int Hi,int Wi,int UP2,int STRIDE,
         int HAS_BN,int RELU,int RES_MODE,int GATE,int WOUT,int OUTF>
__global__ __launch_bounds__(256,2) void conv_mfma_k(
    const bf16* __restrict__ in, const bf16* __restrict__ wTl,
    const float* __restrict__ cbias,
    const float* __restrict__ bng, const float* __restrict__ bnb,
    const void* __restrict__ res, bf16* __restrict__ gate,
    void* __restrict__ out)
{
  constexpr int HWo = Ho * Wo;
  constexpr int Hv = UP2 ? 2*Hi : Hi;
  constexpr int Wv = UP2 ? 2*Wi : Wi;
  __shared__ __align__(16) unsigned short As[2][8192];
  __shared__ __align__(16) unsigned short Bs[2][8192];
  int t = threadIdx.x;
  int nbx = gridDim.x;
  int lin = blockIdx.y * nbx + blockIdx.x;
  int wg  = xcd_swizzle(lin, nbx * gridDim.y);
  int co0 = (wg % nbx) * 128;
  int gp0 = (wg / nbx) * 128;
  int lane = t & 63, wave = t >> 6;
  int wr = (wave >> 1) * 64, wc = (wave & 1) * 64;
  int sr = t >> 1, sk = (t & 1) * 32;
  int swz = (sr & 7) << 4;

  int gp = gp0 + sr;
  int n  = gp / HWo;
  int p  = gp - n * HWo;
  int oy = p / Wo, ox = p - oy * Wo;
  const bf16* wrow = wTl + (size_t)(co0 + sr) * 2304;

  f32x16 acc[2][2];
  #pragma unroll
  for (int i = 0; i < 2; i++)
    #pragma unroll
    for (int j = 0; j < 2; j++)
      #pragma unroll
      for (int r = 0; r < 16; r++) acc[i][j][r] = 0.f;

  uint4 ha[4], hb[4];
  auto issue = [&](int it){
    int tap = it >> 2, sub = it & 3;
    int ky = tap / 3, kx = tap - ky * 3;
    int iy = oy * STRIDE + ky - 1, ix = ox * STRIDE + kx - 1;
    bool val = (iy >= 0) && (iy < Hv) && (ix >= 0) && (ix < Wv);
    int sy = UP2 ? (iy >> 1) : iy;
    int sx = UP2 ? (ix >> 1) : ix;
    if (!val){ sy = 0; sx = 0; }
    const bf16* ap = in + (((size_t)n * Hi + sy) * Wi + sx) * 256 + sub*64 + sk;
    const bf16* bp = wrow + tap * 256 + sub*64 + sk;
    load32(ap, val, ha);
    load32(bp, true, hb);
  };
  auto commit = [&](int buf){
    char* ar = (char*)As[buf] + sr*128;
    char* br = (char*)Bs[buf] + sr*128;
    #pragma unroll
    for (int i = 0; i < 4; i++){
      *reinterpret_cast<uint4*>(ar + ((sk*2 + i*16) ^ swz)) = ha[i];
      *reinterpret_cast<uint4*>(br + ((sk*2 + i*16) ^ swz)) = hb[i];
    }
  };

  issue(0); commit(0);
  __syncthreads();
  #pragma unroll 1
  for (int it = 0; it < 36; ++it){
    if (it + 1 < 36) issue(it + 1);
    mfma_step64((const char*)As[it&1], (const char*)Bs[it&1], wr, wc, lane, acc);
    __syncthreads();
    if (it + 1 < 36) commit((it+1)&1);
    __syncthreads();
  }

  int l31 = lane & 31;
  int rbase = gp0 + wr + ((lane >> 5) << 2);
  #pragma unroll
  for (int j = 0; j < 2; j++){
    int co = co0 + wc + j*32 + l31;
    float cb = cbias[co];
    float scale = 1.f, shift = cb;
    if (HAS_BN){ float g = bng[co]; scale = g; shift = cb*g + bnb[co]; }
    #pragma unroll
    for (int i = 0; i < 2; i++){
      #pragma unroll
      for (int r = 0; r < 16; r++){
        int grow = rbase + i*32 + (r & 3) + ((r >> 2) << 3);
        float v = acc[i][j][r] * scale + shift;
        if (RELU) v = fmaxf(v, 0.f);
        size_t oidx = (size_t)grow * 256 + co;
        if (RES_MODE == 1) v += b2f(((const bf16*)res)[oidx]);
        if (RES_MODE == 2){
          int rn = grow / HWo, rp = grow - rn * HWo;
          v += ((const float*)res)[((size_t)rn * 256 + co) * HWo + rp];
        }
        if (GATE){
          float gv = b2f(gate[oidx]);
          gate[oidx] = f2b(gv / (1.f + __expf(-v)));
        }
        if (WOUT){
          if (OUTF) ((float*)out)[oidx] = v;
          else      ((bf16*)out)[oidx]  = f2b(v);
        }
      }
    }
  }
}

// ------------------------------------------------------------------
// MHA (online softmax). qkv rows (b*S+s), cols [q|k|v] each D=NH*DH.
// ------------------------------------------------------------------
template<int S, int NH, int DH>
__global__ __launch_bounds__(64) void attn_k(
    const bf16* __restrict__ qkv, bf16* __restrict__ out)
{
  const int D = NH * DH;
  int b = blockIdx.x / NH, h = blockIdx.x % NH;
  int chunk = blockIdx.y;
  int lane = threadIdx.x;
  __shared__ float ks[S][DH];
  __shared__ float vs[S][DH];
  __shared__ float os[64][DH];
  for (int idx = lane; idx < S*DH; idx += 64){
    int tt = idx / DH, d = idx % DH;
    size_t row = (size_t)(b*S + tt) * (3*D);
    ks[tt][d] = b2f(qkv[row +   D + h*DH + d]);
    vs[tt][d] = b2f(qkv[row + 2*D + h*DH + d]);
  }
  __syncthreads();
  int s = chunk*64 + lane;
  float q[DH];
  const float scale = 1.f / sqrtf((float)DH);
  if (s < S){
    size_t row = (size_t)(b*S + s) * (3*D);
    #pragma unroll
    for (int d = 0; d < DH; d++) q[d] = b2f(qkv[row + h*DH + d]) * scale;
  } else {
    #pragma unroll
    for (int d = 0; d < DH; d++) q[d] = 0.f;
  }
  float o[DH];
  #pragma unroll
  for (int d = 0; d < DH; d++) o[d] = 0.f;
  float m = -1e30f, l = 0.f;
  for (int tt = 0; tt < S; tt++){
    float sc = 0.f;
    #pragma unroll
    for (int d = 0; d < DH; d++) sc = fmaf(q[d], ks[tt][d], sc);
    float mn = fmaxf(m, sc);
    float corr = __expf(m - mn);
    float e = __expf(sc - mn);
    l = l * corr + e;
    #pragma unroll
    for (int d = 0; d < DH; d++) o[d] = fmaf(o[d], corr, e * vs[tt][d]);
    m = mn;
  }
  float inv = 1.f / l;
  #pragma unroll
  for (int d = 0; d < DH; d++) os[lane][d] = o[d] * inv;
  __syncthreads();
  for (int idx = lane; idx < 64*DH; idx += 64){
    int sl = idx / DH, d = idx % DH;
    int ss = chunk*64 + sl;
    if (ss < S) out[(size_t)(b*S + ss) * D + h*DH + d] = f2b(os[sl][d]);
  }
}

// ------------------------------------------------------------------
// out[r,:] = LN(a[r,:]+b[r,:]) * g + bb  (+ PE[r%49,:] if ADD_PE)
// ------------------------------------------------------------------
template<int ADD_PE, typename TA>
__global__ __launch_bounds__(256) void add_ln_k(
    const TA* __restrict__ a, const bf16* __restrict__ bsrc,
    const float* __restrict__ g, const float* __restrict__ bb, bf16* out)
{
  __shared__ float sred[4];
  int r = blockIdx.x, c = threadIdx.x;
  size_t idx = (size_t)r * 256 + c;
  float x = ldf(a, idx) + b2f(bsrc[idx]);
  float2 mv = block_stats256(x, sred);
  float y = (x - mv.x) * rsqrtf(mv.y + 1e-5f) * g[c] + bb[c];
  if (ADD_PE){
    int s = r % 49;
    float freq = __expf((float)(c & ~1) * (-9.210340371976184f / 256.f));
    float ang = (float)s * freq;
    y += (c & 1) ? cosf(ang) : sinf(ang);
  }
  out[idx] = f2b(y);
}

// ------------------------------------------------------------------
// DynamicConv stage 1: f1[n,s,d] = elu(LN_d(sum_c feats[n,s,c]*p1[n,c,d]))
// k2 is NHWC: k2[(n*49+s)*256+c]
// ------------------------------------------------------------------
__global__ __launch_bounds__(256) void dyn_e1_k(
    const bf16* __restrict__ k2, const bf16* __restrict__ params,
    const float* __restrict__ g, const float* __restrict__ bb,
    bf16* __restrict__ f1)
{
  int n = blockIdx.x;
  int w = threadIdx.x >> 6, d = threadIdx.x & 63;
  const bf16* pp = params + (size_t)n * 32768 + d;
  for (int s = w; s < 49; s += 4){
    const bf16* fp = k2 + ((size_t)n*49 + s) * 256;
    float acc = 0.f;
    #pragma unroll 4
    for (int c = 0; c < 256; c++)
      acc = fmaf(b2f(fp[c]), b2f(pp[c*64]), acc);
    float v = acc;
    #pragma unroll
    for (int o = 32; o; o >>= 1) v += __shfl_xor(v, o);
    float mean = v * (1.f/64.f);
    float dd = acc - mean;
    v = dd * dd;
    #pragma unroll
    for (int o = 32; o; o >>= 1) v += __shfl_xor(v, o);
    float var = v * (1.f/64.f);
    float y = dd * rsqrtf(var + 1e-5f) * g[d] + bb[d];
    y = y > 0.f ? y : (__expf(y) - 1.f);
    f1[((size_t)n*49 + s) * 64 + d] = f2b(y);
  }
}

// ------------------------------------------------------------------
// DynamicConv stage 2 + norm2 (k2 NHWC)
// ------------------------------------------------------------------
__global__ __launch_bounds__(256) void dyn_e2_k(
    const bf16* __restrict__ k2, const bf16* __restrict__ params,
    const bf16* __restrict__ f1,
    const float* __restrict__ g2, const float* __restrict__ bb2,
    const float* __restrict__ ng, const float* __restrict__ nb,
    bf16* __restrict__ obj0)
{
  __shared__ float sred[4];
  int ns = blockIdx.x; int n = ns / 49, s = ns % 49;
  int c = threadIdx.x;
  const bf16* pp  = params + (size_t)n * 32768 + 16384 + c;
  const bf16* f1p = f1 + (size_t)ns * 64;
  float acc = 0.f;
  #pragma unroll 8
  for (int d = 0; d < 64; d++)
    acc = fmaf(b2f(f1p[d]), b2f(pp[d*256]), acc);
  float2 mv = block_stats256(acc, sred);
  float y = (acc - mv.x) * rsqrtf(mv.y + 1e-5f) * g2[c] + bb2[c];
  y = y > 0.f ? y : (__expf(y) - 1.f);
  float pro2 = b2f(k2[((size_t)n*49 + s) * 256 + c]) + y;
  float2 mv2 = block_stats256(pro2, sred);
  float y2 = (pro2 - mv2.x) * rsqrtf(mv2.y + 1e-5f) * ng[c] + nb[c];
  obj0[(size_t)ns * 256 + c] = f2b(y2);
}

// ------------------------------------------------------------------
// gate at 7x7 (all NHWC): rec7 = k2 * sigmoid(obj)
// ------------------------------------------------------------------
__global__ __launch_bounds__(256) void gate7_k(
    const bf16* __restrict__ k2, const bf16* __restrict__ obj,
    bf16* __restrict__ rec7)
{
  size_t idx = (size_t)blockIdx.x * 256 + threadIdx.x;
  float ov = b2f(obj[idx]);
  rec7[idx] = f2b(b2f(k2[idx]) / (1.f + __expf(-ov)));
}

// ==================================================================
extern "C" void kernel_launch(void* const* d_in, const int* in_sizes, int n_in,
                              void* d_out, int out_size, void* d_ws, size_t ws_size,
                              hipStream_t stream)
{
  (void)hipGetLastError();  // clear stale errors

  static float h_sent[64];
  auto send_sentinel = [&](float val){
    for (int i = 0; i < 64; i++) h_sent[i] = val;
    hipMemcpyAsync(d_out, h_sent, 256, hipMemcpyHostToDevice, stream);
  };

  static const int EXP_SIZES[53] = {
    25690112, 32768, 100352, 1179648, 512, 512, 512, 196608, 768, 65536,
    256, 256, 256, 256, 256, 256, 256, 8388608, 32768, 64,
    64, 256, 256, 524288, 2048, 524288, 256, 589824, 2304, 196608,
    768, 768, 768, 768, 768, 1572864, 6144, 1572864, 768, 1179648,
    512, 512, 512, 1179648, 512, 512, 512, 1179648, 512, 589824,
    256, 256, 256 };
  if (n_in != 53){ send_sentinel(6600.f + (float)n_in); return; }
  for (int i = 0; i < 53; i++)
    if (in_sizes[i] != EXP_SIZES[i]){ send_sentinel(6000.f + 10.f*i); return; }
  if (out_size != 25690112){ send_sentinel(3000.f + (float)(out_size >> 20)); return; }
  if (ws_size < 77070400ull){ send_sentinel(2000.f + (float)(ws_size >> 20)); return; }

  const float* roi    = (const float*)d_in[0];
  const float* proF   = (const float*)d_in[1];
  const float* encW   = (const float*)d_in[3];
  const float* encB   = (const float*)d_in[4];
  const float* encG   = (const float*)d_in[5];
  const float* encBB  = (const float*)d_in[6];
  const float* aqkvW  = (const float*)d_in[7];
  const float* aqkvB  = (const float*)d_in[8];
  const float* aoutW  = (const float*)d_in[9];
  const float* aoutB  = (const float*)d_in[10];
  const float* n1g    = (const float*)d_in[11];
  const float* n1b    = (const float*)d_in[12];
  const float* n2g    = (const float*)d_in[13];
  const float* n2b    = (const float*)d_in[14];
  const float* n3g    = (const float*)d_in[15];
  const float* n3b    = (const float*)d_in[16];
  const float* dynW   = (const float*)d_in[17];
  const float* dynB   = (const float*)d_in[18];
  const float* dn1g   = (const float*)d_in[19];
  const float* dn1b   = (const float*)d_in[20];
  const float* dn2g   = (const float*)d_in[21];
  const float* dn2b   = (const float*)d_in[22];
  const float* lin1W  = (const float*)d_in[23];
  const float* lin1B  = (const float*)d_in[24];
  const float* lin2W  = (const float*)d_in[25];
  const float* lin2B  = (const float*)d_in[26];
  const float* teqkvW = (const float*)d_in[27];
  const float* teqkvB = (const float*)d_in[28];
  const float* teoutW = (const float*)d_in[29];
  const float* teoutB = (const float*)d_in[30];
  const float* teln1g = (const float*)d_in[31];
  const float* teln1b = (const float*)d_in[32];
  const float* teln2g = (const float*)d_in[33];
  const float* teln2b = (const float*)d_in[34];
  const float* teff1W = (const float*)d_in[35];
  const float* teff1B = (const float*)d_in[36];
  const float* teff2W = (const float*)d_in[37];
  const float* teff2B = (const float*)d_in[38];
  const float* recW   = (const float*)d_in[39];
  const float* recB   = (const float*)d_in[40];
  const float* recG   = (const float*)d_in[41];
  const float* recBB  = (const float*)d_in[42];
  const float* dAW    = (const float*)d_in[43];
  const float* dAB    = (const float*)d_in[44];
  const float* dAG    = (const float*)d_in[45];
  const float* dABB   = (const float*)d_in[46];
  const float* dBW    = (const float*)d_in[47];
  const float* dBB_   = (const float*)d_in[48];
  const float* dfW    = (const float*)d_in[49];
  const float* dfB    = (const float*)d_in[50];
  const float* dfG    = (const float*)d_in[51];
  const float* dfBB   = (const float*)d_in[52];

  // ---- workspace layout (bf16 elems). ws >= 77,070,400 bytes. ----
  bf16* base   = (bf16*)d_ws;
  bf16* wT     = base + 0;         //  5,308,416 (9 x 589,824), whole launch
  bf16* k1     = base + 5308416;   //  6,422,528  NHWC 14x14 (dead after detB-14)
  bf16* k2     = base + 11730944;  //  1,605,632  NHWC 7x7
  bf16* qkvP   = base + 13336576;  //     98,304
  bf16* attoP  = base + 13434880;  //     32,768
  bf16* mhaP   = base + 13467648;  //     32,768
  bf16* proQ   = base + 13500416;  //     32,768
  bf16* f1     = base + 13533184;  //    401,408
  bf16* obj0   = base + 13934592;  //  1,605,632
  bf16* tmp    = base + 15540224;  //  1,605,632
  bf16* atto   = base + 17145856;  //  1,605,632
  bf16* obj    = base + 18751488;  //  1,605,632 (dead after detA 7->14)
  bf16* params = base + 20357120;  //  4,194,304 (dead after dyn_e2)
  bf16* rec7   = base + 20357120;  //  1,605,632 alias over params
  bf16* hbuf   = base + 24551424;  // 12,845,056 (FFN/TE only)
  bf16* qkvT   = base + 24551424;  //  4,816,896 alias over hbuf
  bf16* C14    = base + 24551424;  //  6,422,528 alias over hbuf (dead after detB-14)
  bf16* B14    = base + 32112640;  //  6,422,528 (ends exactly at 38,535,168)
  bf16* B28    = base + 5308416;   // 25,690,112 alias over k1..C14 region (all dead)
  // d_out (102.76 MB) as staged scratch, all dead before final fp32 write:
  bf16* roiT   = (bf16*)d_out;             // 25,690,112 (dead after enc conv1)
  bf16* A14    = (bf16*)d_out;             //  6,422,528 (written step4, read step6)
  bf16* C28    = (bf16*)d_out + 6422528;   // 25,690,112
  float* score = (float*)((char*)d_ws + 77070336);  // 14-float scoreboard

  // ---- layout transposes (once per call) ----
  troi_k<<<dim3(13,4,128),256,0,stream>>>(roi, roiT);
  wtrans_k<<<256,256,0,stream>>>(encW,            wT + 0*589824);
  wtrans_k<<<256,256,0,stream>>>(encW + 589824,   wT + 1*589824);
  wtrans_k<<<256,256,0,stream>>>(recW,            wT + 2*589824);
  wtrans_k<<<256,256,0,stream>>>(recW + 589824,   wT + 3*589824);
  wtrans_k<<<256,256,0,stream>>>(dAW,             wT + 4*589824);
  wtrans_k<<<256,256,0,stream>>>(dAW + 589824,    wT + 5*589824);
  wtrans_k<<<256,256,0,stream>>>(dBW,             wT + 6*589824);
  wtrans_k<<<256,256,0,stream>>>(dBW + 589824,    wT + 7*589824);
  wtrans_k<<<256,256,0,stream>>>(dfW,             wT + 8*589824);
  probe_k<<<1,256,0,stream>>>(roiT, 25690112ull, score+0);

  // ---- k_encoder: 28 -> 14 -> 7 (NHWC) ----
  conv_mfma_k<14,14,28,28,0,2, 1,1,0,0,1,0><<<dim3(2,196),256,0,stream>>>(
      roiT, wT + 0*589824, encB, encG, encBB, nullptr, nullptr, k1);
  probe_k<<<1,256,0,stream>>>(k1, 6422528ull, score+1);
  conv_mfma_k<7,7,14,14,0,2, 1,1,0,0,1,0><<<dim3(2,49),256,0,stream>>>(
      k1, wT + 1*589824, encB+256, encG+256, encBB+256, nullptr, nullptr, k2);
  probe_k<<<1,256,0,stream>>>(k2, 1605632ull, score+2);

  // ---- self-attention over 128 query tokens ----
  gemm_mfma_k<0,float><<<dim3(6,1),256,0,stream>>>(proF, aqkvW, aqkvB, qkvP, 128,768,256);
  probe_k<<<1,256,0,stream>>>(qkvP, 98304ull, score+3);
  attn_k<128,8,32><<<dim3(8,2),64,0,stream>>>(qkvP, attoP);
  gemm_mfma_k<0,bf16><<<dim3(2,1),256,0,stream>>>(attoP, aoutW, aoutB, mhaP, 128,256,256);
  add_ln_k<0,float><<<128,256,0,stream>>>(proF, mhaP, n1g, n1b, proQ);
  probe_k<<<1,256,0,stream>>>(proQ, 32768ull, score+4);

  // ---- DynamicConv ----
  gemm_mfma_k<0,bf16><<<dim3(256,1),256,0,stream>>>(proQ, dynW, dynB, params, 128,32768,256);
  probe_k<<<1,256,0,stream>>>(params, 4194304ull, score+5);
  dyn_e1_k<<<128,256,0,stream>>>(k2, params, dn1g, dn1b, f1);
  probe_k<<<1,256,0,stream>>>(f1, 401408ull, score+6);
  dyn_e2_k<<<6272,256,0,stream>>>(k2, params, f1, dn2g, dn2b, n2g, n2b, obj0);
  probe_k<<<1,256,0,stream>>>(obj0, 1605632ull, score+7);

  // ---- FFN (ELU) + norm3 + PE ----
  gemm_mfma_k<2,bf16><<<dim3(16,49),256,0,stream>>>(obj0, lin1W, lin1B, hbuf, 6272,2048,256);
  gemm_mfma_k<0,bf16><<<dim3(2,49),256,0,stream>>>(hbuf, lin2W, lin2B, tmp, 6272,256,2048);
  add_ln_k<1,bf16><<<6272,256,0,stream>>>(obj0, tmp, n3g, n3b, obj);
  probe_k<<<1,256,0,stream>>>(obj, 1605632ull, score+8);

  // ---- 3-layer TransformerEncoder (post-norm, relu, nh=4) ----
  for (int l = 0; l < 3; l++){
    gemm_mfma_k<0,bf16><<<dim3(6,49),256,0,stream>>>(
        obj, teqkvW + (size_t)l*196608, teqkvB + l*768, qkvT, 6272,768,256);
    attn_k<49,4,64><<<dim3(512,1),64,0,stream>>>(qkvT, atto);
    gemm_mfma_k<0,bf16><<<dim3(2,49),256,0,stream>>>(
        atto, teoutW + (size_t)l*65536, teoutB + l*256, tmp, 6272,256,256);
    add_ln_k<0,bf16><<<6272,256,0,stream>>>(obj, tmp, teln1g + l*256, teln1b + l*256, obj);
    gemm_mfma_k<1,bf16><<<dim3(16,49),256,0,stream>>>(
        obj, teff1W + (size_t)l*524288, teff1B + l*2048, hbuf, 6272,2048,256);
    gemm_mfma_k<0,bf16><<<dim3(2,49),256,0,stream>>>(
        hbuf, teff2W + (size_t)l*524288, teff2B + l*256, tmp, 6272,256,2048);
    add_ln_k<0,bf16><<<6272,256,0,stream>>>(obj, tmp, teln2g + l*256, teln2b + l*256, obj);
  }
  probe_k<<<1,256,0,stream>>>(obj, 1605632ull, score+9);

  // ---- gated rec/det decoder pyramid (all NHWC) ----
  gate7_k<<<6272,256,0,stream>>>(k2, obj, rec7);
  probe_k<<<1,256,0,stream>>>(rec7, 1605632ull, score+10);
  // 7 -> 14
  conv_mfma_k<14,14,7,7,1,1, 1,1,1,0,1,0><<<dim3(2,196),256,0,stream>>>(
      rec7, wT + 2*589824, recB, recG, recBB, k1, nullptr, B14);
  probe_k<<<1,256,0,stream>>>(B14, 6422528ull, score+11);
  conv_mfma_k<14,14,7,7,1,1, 1,1,0,0,1,0><<<dim3(2,196),256,0,stream>>>(
      obj, wT + 4*589824, dAB, dAG, dABB, nullptr, nullptr, C14);
  conv_mfma_k<14,14,14,14,0,1, 0,0,1,1,1,0><<<dim3(2,196),256,0,stream>>>(
      C14, wT + 6*589824, dBB_, nullptr, nullptr, k1, B14, A14);
  probe_k<<<1,256,0,stream>>>(A14, 6422528ull, score+12);
  // 14 -> 28
  conv_mfma_k<28,28,14,14,1,1, 1,1,2,0,1,0><<<dim3(2,784),256,0,stream>>>(
      B14, wT + 3*589824, recB+256, recG+256, recBB+256, roi, nullptr, B28);
  probe_k<<<1,256,0,stream>>>(B28, 25690112ull, score+13);
  conv_mfma_k<28,28,14,14,1,1, 1,1,0,0,1,0><<<dim3(2,784),256,0,stream>>>(
      A14, wT + 5*589824, dAB+256, dAG+256, dABB+256, nullptr, nullptr, C28);
  conv_mfma_k<28,28,28,28,0,1, 0,0,2,1,0,0><<<dim3(2,784),256,0,stream>>>(
      C28, wT + 7*589824, dBB_+256, nullptr, nullptr, roi, B28, nullptr);
  // final conv + BN + ReLU, FP32 NHWC into d_out
  conv_mfma_k<28,28,28,28,0,1, 1,1,0,0,1,1><<<dim3(2,784),256,0,stream>>>(
      B28, wT + 8*589824, dfB, dfG, dfBB, nullptr, nullptr, d_out);

  // ---- verdict + launch-error readout ----
  verdict_k<<<1,64,0,stream>>>(score, 14, (float*)d_out);
  hipError_t le = hipGetLastError();
  if (le != hipSuccess){
    float v = 7000.f + 16.f * (float)(int)le;
    if (v > 60000.f) v = 60000.f;
    send_sentinel(v);
  }
}

// Round 3
// 2453.940 us; speedup vs baseline: 1.1917x; 1.1917x over previous
//
#include <hip/hip_runtime.h>
#include <hip/hip_bf16.h>
#include <string.h>

typedef __hip_bfloat16 bf16;
typedef short bf16x8 __attribute__((ext_vector_type(8)));
typedef float f32x16 __attribute__((ext_vector_type(16)));

typedef __attribute__((address_space(3))) unsigned int       as3_u32;
typedef const __attribute__((address_space(1))) unsigned int as1_u32c;

__device__ __forceinline__ void dma16(const void* g, void* l){
  __builtin_amdgcn_global_load_lds((as1_u32c*)g, (as3_u32*)l, 16, 0, 0);
}

// 256B of zeros for conv padding rows (device globals are zero-initialized)
__device__ __align__(256) unsigned char g_zpad[256];

__device__ __forceinline__ float b2f(bf16 v){ return __bfloat162float(v); }
__device__ __forceinline__ bf16  f2b(float v){ return __float2bfloat16(v); }
__device__ __forceinline__ unsigned short f2bu(float v){
  union { bf16 b; unsigned short u; } x; x.b = __float2bfloat16(v); return x.u;
}
__device__ __forceinline__ float ldf(const float* p, size_t i){ return p[i]; }
__device__ __forceinline__ float ldf(const bf16*  p, size_t i){ return b2f(p[i]); }

// bijective XCD-aware block remap (m204): chunk-contiguous per XCD
__device__ __forceinline__ int xcd_swizzle(int lin, int nwg){
  int q = nwg >> 3, r = nwg & 7;
  int x = lin & 7, i = lin >> 3;
  int base = (x < r) ? x * (q + 1) : r * (q + 1) + (x - r) * q;
  return base + i;
}

// ------------------------------------------------------------------
// block-wide (256 thr) mean/var helper. sred must be float[4] shared.
// ------------------------------------------------------------------
__device__ __forceinline__ float2 block_stats256(float x, float* sred){
  float v = x;
  #pragma unroll
  for (int o = 32; o; o >>= 1) v += __shfl_xor(v, o);
  int w = threadIdx.x >> 6;
  if ((threadIdx.x & 63) == 0) sred[w] = v;
  __syncthreads();
  float mean = (sred[0] + sred[1] + sred[2] + sred[3]) * (1.f/256.f);
  __syncthreads();
  float d = x - mean;
  v = d * d;
  #pragma unroll
  for (int o = 32; o; o >>= 1) v += __shfl_xor(v, o);
  if ((threadIdx.x & 63) == 0) sred[w] = v;
  __syncthreads();
  float var = (sred[0] + sred[1] + sred[2] + sred[3]) * (1.f/256.f);
  __syncthreads();
  return make_float2(mean, var);
}

// ---- diagnostics ----
__global__ __launch_bounds__(256) void probe_k(const bf16* __restrict__ buf,
                                               unsigned long long len, float* score){
  __shared__ float sred[4];
  unsigned long long stride = len / 256ull; if (!stride) stride = 1;
  unsigned long long i = (unsigned long long)threadIdx.x * stride;
  if (i >= len) i = len - 1;
  float v = fabsf(b2f(buf[i]));
  #pragma unroll
  for (int o = 32; o; o >>= 1) v = fmaxf(v, __shfl_xor(v, o));
  if ((threadIdx.x & 63) == 0) sred[threadIdx.x >> 6] = v;
  __syncthreads();
  if (threadIdx.x == 0)
    score[0] = fmaxf(fmaxf(sred[0], sred[1]), fmaxf(sred[2], sred[3]));
}

__global__ void verdict_k(const float* score, int nstage, float* out){
  if (threadIdx.x == 0 && blockIdx.x == 0){
    for (int i = 0; i < nstage; i++){
      float s = score[i];
      if (!(s > 1e-8f)){
        float sent = 1000.f + 40.f * i;
        for (int j = 0; j < 64; j++) out[j] = sent;
        return;
      }
    }
  }
}

// ------------------------------------------------------------------
// fp32 -> bf16 bulk convert (n/4 float4s)
// ------------------------------------------------------------------
__global__ __launch_bounds__(256) void cvt_k(const float* __restrict__ s,
                                             bf16* __restrict__ d, int n4){
  int i = blockIdx.x * 256 + threadIdx.x;
  if (i < n4){
    float4 f = reinterpret_cast<const float4*>(s)[i];
    ushort4 u;
    u.x = f2bu(f.x); u.y = f2bu(f.y); u.z = f2bu(f.z); u.w = f2bu(f.w);
    reinterpret_cast<ushort4*>(d)[i] = u;
  }
}

// ------------------------------------------------------------------
// transpose roi (fp32 NCHW 28x28) -> bf16 NHWC
// ------------------------------------------------------------------
__global__ __launch_bounds__(256) void troi_k(const float* __restrict__ roi,
                                              bf16* __restrict__ o){
  __shared__ float tile[64][65];
  int n = blockIdx.z, c0 = blockIdx.y * 64, p0 = blockIdx.x * 64;
  int a = threadIdx.x & 63, bq = threadIdx.x >> 6;
  #pragma unroll
  for (int cs = bq; cs < 64; cs += 4){
    int p = p0 + a;
    tile[cs][a] = (p < 784) ? roi[((size_t)n*256 + c0 + cs)*784 + p] : 0.f;
  }
  __syncthreads();
  #pragma unroll
  for (int ps = bq; ps < 64; ps += 4){
    int p = p0 + ps;
    if (p < 784) o[((size_t)n*784 + p)*256 + c0 + a] = f2b(tile[a][ps]);
  }
}

// ------------------------------------------------------------------
// weight transpose: w[co][ci][tap] fp32 -> wT[co][tap*256+ci] bf16
// ------------------------------------------------------------------
__global__ __launch_bounds__(256) void wtrans_k(const float* __restrict__ w,
                                                bf16* __restrict__ o){
  int co = blockIdx.x, t = threadIdx.x;
  const float* wp = w + (size_t)co * 2304 + (size_t)t * 9;
  #pragma unroll
  for (int tap = 0; tap < 9; tap++)
    o[(size_t)co * 2304 + tap * 256 + t] = f2b(wp[tap]);
}

// ------------------------------------------------------------------
// MFMA tile compute (128x128 block tile, 4 waves of 64x64, K-step 64)
// LDS row = 64 bf16 = 128B; 16B chunks XOR-permuted by ((row&7)<<4).
// (DMA writes LDS LINEARLY; the permutation is applied on the per-lane
//  GLOBAL source address at stage time, and again at read time.)
// ------------------------------------------------------------------
__device__ __forceinline__ void mfma_step64(const unsigned short* As,
                                            const unsigned short* Bs,
                                            int wr, int wc, int lane,
                                            f32x16 (&acc)[2][2]){
  const char* asb = (const char*)As;
  const char* bsb = (const char*)Bs;
  int l31 = lane & 31;
  int lsw = (l31 & 7) << 4;
  int hi  = (lane >> 5) << 4;
  #pragma unroll
  for (int kb = 0; kb < 4; kb++){
    int cb = (kb*32 + hi) ^ lsw;
    bf16x8 a0 = *reinterpret_cast<const bf16x8*>(asb + (wr      + l31)*128 + cb);
    bf16x8 a1 = *reinterpret_cast<const bf16x8*>(asb + (wr + 32 + l31)*128 + cb);
    bf16x8 b0 = *reinterpret_cast<const bf16x8*>(bsb + (wc      + l31)*128 + cb);
    bf16x8 b1 = *reinterpret_cast<const bf16x8*>(bsb + (wc + 32 + l31)*128 + cb);
    acc[0][0] = __builtin_amdgcn_mfma_f32_32x32x16_bf16(a0, b0, acc[0][0], 0, 0, 0);
    acc[0][1] = __builtin_amdgcn_mfma_f32_32x32x16_bf16(a0, b1, acc[0][1], 0, 0, 0);
    acc[1][0] = __builtin_amdgcn_mfma_f32_32x32x16_bf16(a1, b0, acc[1][0], 0, 0, 0);
    acc[1][1] = __builtin_amdgcn_mfma_f32_32x32x16_bf16(a1, b1, acc[1][1], 0, 0, 0);
  }
}

// ------------------------------------------------------------------
// MFMA NT GEMM: C[M,N] = act(A[M,K] @ W[N,K]^T + bias), all bf16 in.
// M%128==0, N%128==0, K%64==0. DMA-staged, dbuf, 1 barrier / K-step.
// ------------------------------------------------------------------
template<int ACT>
__global__ __launch_bounds__(256) void gemm_mfma_k(
    const bf16* __restrict__ A, const bf16* __restrict__ W,
    const float* __restrict__ bias, bf16* __restrict__ C,
    int M, int N, int K)
{
  __shared__ __align__(16) unsigned short As[2][8192];
  __shared__ __align__(16) unsigned short Bs[2][8192];
  int t = threadIdx.x;
  int nbx = gridDim.x;
  int lin = blockIdx.y * nbx + blockIdx.x;
  int wg  = xcd_swizzle(lin, nbx * gridDim.y);
  int n0 = (wg % nbx) * 128, m0 = (wg / nbx) * 128;
  int lane = t & 63, wave = t >> 6;
  int wr = (wave >> 1) * 64, wc = (wave & 1) * 64;
  int lrow = lane >> 3;                         // 0..7: row within 8-row DMA group
  int e0   = (((lane & 7) ^ lrow) << 3);        // src element offset (inverse swizzle)

  f32x16 acc[2][2];
  #pragma unroll
  for (int i = 0; i < 2; i++)
    #pragma unroll
    for (int j = 0; j < 2; j++)
      #pragma unroll
      for (int r = 0; r < 16; r++) acc[i][j][r] = 0.f;

  const bf16* apr[4]; const bf16* bpr[4];
  #pragma unroll
  for (int i = 0; i < 4; i++){
    int r = wave*32 + i*8 + lrow;
    apr[i] = A + (size_t)(m0 + r) * K + e0;
    bpr[i] = W + (size_t)(n0 + r) * K + e0;
  }

  auto stage = [&](int buf, int k0){
    #pragma unroll
    for (int i = 0; i < 4; i++){
      dma16(apr[i] + k0, &As[buf][(wave*32 + i*8) * 64]);
      dma16(bpr[i] + k0, &Bs[buf][(wave*32 + i*8) * 64]);
    }
  };

  int NIT = K >> 6;
  stage(0, 0);
  __syncthreads();
  #pragma unroll 1
  for (int it = 0; it < NIT; ++it){
    if (it + 1 < NIT) stage((it+1)&1, (it+1)*64);
    mfma_step64(As[it&1], Bs[it&1], wr, wc, lane, acc);
    __syncthreads();
  }

  int l31 = lane & 31;
  int rbase = m0 + wr + ((lane >> 5) << 2);
  #pragma unroll
  for (int j = 0; j < 2; j++){
    int n = n0 + wc + j*32 + l31;
    float bv = bias ? bias[n] : 0.f;
    #pragma unroll
    for (int i = 0; i < 2; i++){
      #pragma unroll
      for (int r = 0; r < 16; r++){
        int row = rbase + i*32 + (r & 3) + ((r >> 2) << 3);
        float v = acc[i][j][r] + bv;
        if (ACT == 1) v = fmaxf(v, 0.f);
        if (ACT == 2) v = v > 0.f ? v : (__expf(v) - 1.f);
        C[(size_t)row * N + n] = f2b(v);
      }
    }
  }
}

// ------------------------------------------------------------------
// MFMA 3x3 conv, Cin=Cout=256, pad 1, NHWC bf16 in/out, batch=128.
// Implicit GEMM: rows = (n*HWo+p), cols = co, K=2304 (36 steps of 64).
// DMA-staged, dbuf, 1 barrier / K-step; pad rows DMA from g_zpad.
// RES_MODE: 0 none, 1 bf16 NHWC, 2 fp32 NCHW.
// ------------------------------------------------------------------
template<int Ho,int Wo,int Hi,int Wi,int UP2,int STRIDE,
         int HAS_BN,int RELU,int RES_MODE,int GATE,int WOUT,int OUTF>
__global__ __launch_bounds__(256) void conv_mfma_k(
    const bf16* __restrict__ in, const bf16* __restrict__ wTl,
    const float* __restrict__ cbias,
    const float* __restrict__ bng, const float* __restrict__ bnb,
    const void* __restrict__ res, bf16* __restrict__ gate,
    void* __restrict__ out)
{
  constexpr int HWo = Ho * Wo;
  constexpr int Hv = UP2 ? 2*Hi : Hi;
  constexpr int Wv = UP2 ? 2*Wi : Wi;
  __shared__ __align__(16) unsigned short As[2][8192];
  __shared__ __align__(16) unsigned short Bs[2][8192];
  int t = threadIdx.x;
  int nbx = gridDim.x;
  int lin = blockIdx.y * nbx + blockIdx.x;
  int wg  = xcd_swizzle(lin, nbx * gridDim.y);
  int co0 = (wg % nbx) * 128;
  int gp0 = (wg / nbx) * 128;
  int lane = t & 63, wave = t >> 6;
  int wr = (wave >> 1) * 64, wc = (wave & 1) * 64;
  int lrow = lane >> 3;
  int e0   = (((lane & 7) ^ lrow) << 3);

  // per-thread geometry of its 4 staged A-rows / B-rows
  int nA[4], oyA[4], oxA[4]; size_t wbase[4];
  #pragma unroll
  for (int i = 0; i < 4; i++){
    int r  = wave*32 + i*8 + lrow;
    int gp = gp0 + r;
    nA[i] = gp / HWo;
    int p = gp - nA[i] * HWo;
    oyA[i] = p / Wo; oxA[i] = p - oyA[i] * Wo;
    wbase[i] = (size_t)(co0 + r) * 2304;
  }

  f32x16 acc[2][2];
  #pragma unroll
  for (int i = 0; i < 2; i++)
    #pragma unroll
    for (int j = 0; j < 2; j++)
      #pragma unroll
      for (int r = 0; r < 16; r++) acc[i][j][r] = 0.f;

  auto stage = [&](int buf, int it){
    int tap = it >> 2, sub = it & 3;
    int ky = tap / 3, kx = tap - ky * 3;
    #pragma unroll
    for (int i = 0; i < 4; i++){
      int iy = oyA[i]*STRIDE + ky - 1;
      int ix = oxA[i]*STRIDE + kx - 1;
      bool val = (iy >= 0) && (iy < Hv) && (ix >= 0) && (ix < Wv);
      int sy = UP2 ? (iy >> 1) : iy;
      int sx = UP2 ? (ix >> 1) : ix;
      const bf16* sa = val
        ? in + (((size_t)nA[i] * Hi + sy) * Wi + sx) * 256 + sub*64 + e0
        : (const bf16*)g_zpad + e0;
      dma16(sa, &As[buf][(wave*32 + i*8) * 64]);
      const bf16* sb = wTl + wbase[i] + tap*256 + sub*64 + e0;
      dma16(sb, &Bs[buf][(wave*32 + i*8) * 64]);
    }
  };

  stage(0, 0);
  __syncthreads();
  #pragma unroll 1
  for (int it = 0; it < 36; ++it){
    if (it + 1 < 36) stage((it+1)&1, it+1);
    mfma_step64(As[it&1], Bs[it&1], wr, wc, lane, acc);
    __syncthreads();
  }

  int l31 = lane & 31;
  int rbase = gp0 + wr + ((lane >> 5) << 2);
  #pragma unroll
  for (int j = 0; j < 2; j++){
    int co = co0 + wc + j*32 + l31;
    float cb = cbias[co];
    float scale = 1.f, shift = cb;
    if (HAS_BN){ float g = bng[co]; scale = g; shift = cb*g + bnb[co]; }
    #pragma unroll
    for (int i = 0; i < 2; i++){
      #pragma unroll
      for (int r = 0; r < 16; r++){
        int grow = rbase + i*32 + (r & 3) + ((r >> 2) << 3);
        float v = acc[i][j][r] * scale + shift;
        if (RELU) v = fmaxf(v, 0.f);
        size_t oidx = (size_t)grow * 256 + co;
        if (RES_MODE == 1) v += b2f(((const bf16*)res)[oidx]);
        if (RES_MODE == 2){
          int rn = grow / HWo, rp = grow - rn * HWo;
          v += ((const float*)res)[((size_t)rn * 256 + co) * HWo + rp];
        }
        if (GATE){
          float gv = b2f(gate[oidx]);
          gate[oidx] = f2b(gv / (1.f + __expf(-v)));
        }
        if (WOUT){
          if (OUTF) ((float*)out)[oidx] = v;
          else      ((bf16*)out)[oidx]  = f2b(v);
        }
      }
    }
  }
}

// ------------------------------------------------------------------
// MHA (online softmax). qkv rows (b*S+s), cols [q|k|v] each D=NH*DH.
// ------------------------------------------------------------------
template<int S, int NH, int DH>
__global__ __launch_bounds__(64) void attn_k(
    const bf16* __restrict__ qkv, bf16* __restrict__ out)
{
  const int D = NH * DH;
  int b = blockIdx.x / NH, h = blockIdx.x % NH;
  int chunk = blockIdx.y;
  int lane = threadIdx.x;
  __shared__ float ks[S][DH];
  __shared__ float vs[S][DH];
  __shared__ float os[64][DH];
  for (int idx = lane; idx < S*DH; idx += 64){
    int tt = idx / DH, d = idx % DH;
    size_t row = (size_t)(b*S + tt) * (3*D);
    ks[tt][d] = b2f(qkv[row +   D + h*DH + d]);
    vs[tt][d] = b2f(qkv[row + 2*D + h*DH + d]);
  }
  __syncthreads();
  int s = chunk*64 + lane;
  float q[DH];
  const float scale = 1.f / sqrtf((float)DH);
  if (s < S){
    size_t row = (size_t)(b*S + s) * (3*D);
    #pragma unroll
    for (int d = 0; d < DH; d++) q[d] = b2f(qkv[row + h*DH + d]) * scale;
  } else {
    #pragma unroll
    for (int d = 0; d < DH; d++) q[d] = 0.f;
  }
  float o[DH];
  #pragma unroll
  for (int d = 0; d < DH; d++) o[d] = 0.f;
  float m = -1e30f, l = 0.f;
  for (int tt = 0; tt < S; tt++){
    float sc = 0.f;
    #pragma unroll
    for (int d = 0; d < DH; d++) sc = fmaf(q[d], ks[tt][d], sc);
    float mn = fmaxf(m, sc);
    float corr = __expf(m - mn);
    float e = __expf(sc - mn);
    l = l * corr + e;
    #pragma unroll
    for (int d = 0; d < DH; d++) o[d] = fmaf(o[d], corr, e * vs[tt][d]);
    m = mn;
  }
  float inv = 1.f / l;
  #pragma unroll
  for (int d = 0; d < DH; d++) os[lane][d] = o[d] * inv;
  __syncthreads();
  for (int idx = lane; idx < 64*DH; idx += 64){
    int sl = idx / DH, d = idx % DH;
    int ss = chunk*64 + sl;
    if (ss < S) out[(size_t)(b*S + ss) * D + h*DH + d] = f2b(os[sl][d]);
  }
}

// ------------------------------------------------------------------
// out[r,:] = LN(a[r,:]+b[r,:]) * g + bb  (+ PE[r%49,:] if ADD_PE)
// ------------------------------------------------------------------
template<int ADD_PE, typename TA>
__global__ __launch_bounds__(256) void add_ln_k(
    const TA* __restrict__ a, const bf16* __restrict__ bsrc,
    const float* __restrict__ g, const float* __restrict__ bb, bf16* out)
{
  __shared__ float sred[4];
  int r = blockIdx.x, c = threadIdx.x;
  size_t idx = (size_t)r * 256 + c;
  float x = ldf(a, idx) + b2f(bsrc[idx]);
  float2 mv = block_stats256(x, sred);
  float y = (x - mv.x) * rsqrtf(mv.y + 1e-5f) * g[c] + bb[c];
  if (ADD_PE){
    int s = r % 49;
    float freq = __expf((float)(c & ~1) * (-9.210340371976184f / 256.f));
    float ang = (float)s * freq;
    y += (c & 1) ? cosf(ang) : sinf(ang);
  }
  out[idx] = f2b(y);
}

// ------------------------------------------------------------------
// DynamicConv stage 1: f1[n,s,d] = elu(LN_d(sum_c feats[n,s,c]*p1[n,c,d]))
// ------------------------------------------------------------------
__global__ __launch_bounds__(256) void dyn_e1_k(
    const bf16* __restrict__ k2, const bf16* __restrict__ params,
    const float* __restrict__ g, const float* __restrict__ bb,
    bf16* __restrict__ f1)
{
  int n = blockIdx.x;
  int w = threadIdx.x >> 6, d = threadIdx.x & 63;
  const bf16* pp = params + (size_t)n * 32768 + d;
  for (int s = w; s < 49; s += 4){
    const bf16* fp = k2 + ((size_t)n*49 + s) * 256;
    float acc = 0.f;
    #pragma unroll 4
    for (int c = 0; c < 256; c++)
      acc = fmaf(b2f(fp[c]), b2f(pp[c*64]), acc);
    float v = acc;
    #pragma unroll
    for (int o = 32; o; o >>= 1) v += __shfl_xor(v, o);
    float mean = v * (1.f/64.f);
    float dd = acc - mean;
    v = dd * dd;
    #pragma unroll
    for (int o = 32; o; o >>= 1) v += __shfl_xor(v, o);
    float var = v * (1.f/64.f);
    float y = dd * rsqrtf(var + 1e-5f) * g[d] + bb[d];
    y = y > 0.f ? y : (__expf(y) - 1.f);
    f1[((size_t)n*49 + s) * 64 + d] = f2b(y);
  }
}

// ------------------------------------------------------------------
// DynamicConv stage 2 + norm2 (k2 NHWC)
// ------------------------------------------------------------------
__global__ __launch_bounds__(256) void dyn_e2_k(
    const bf16* __restrict__ k2, const bf16* __restrict__ params,
    const bf16* __restrict__ f1,
    const float* __restrict__ g2, const float* __restrict__ bb2,
    const float* __restrict__ ng, const float* __restrict__ nb,
    bf16* __restrict__ obj0)
{
  __shared__ float sred[4];
  int ns = blockIdx.x; int n = ns / 49, s = ns % 49;
  int c = threadIdx.x;
  const bf16* pp  = params + (size_t)n * 32768 + 16384 + c;
  const bf16* f1p = f1 + (size_t)ns * 64;
  float acc = 0.f;
  #pragma unroll 8
  for (int d = 0; d < 64; d++)
    acc = fmaf(b2f(f1p[d]), b2f(pp[d*256]), acc);
  float2 mv = block_stats256(acc, sred);
  float y = (acc - mv.x) * rsqrtf(mv.y + 1e-5f) * g2[c] + bb2[c];
  y = y > 0.f ? y : (__expf(y) - 1.f);
  float pro2 = b2f(k2[((size_t)n*49 + s) * 256 + c]) + y;
  float2 mv2 = block_stats256(pro2, sred);
  float y2 = (pro2 - mv2.x) * rsqrtf(mv2.y + 1e-5f) * ng[c] + nb[c];
  obj0[(size_t)ns * 256 + c] = f2b(y2);
}

// ------------------------------------------------------------------
// gate at 7x7 (all NHWC): rec7 = k2 * sigmoid(obj)
// ------------------------------------------------------------------
__global__ __launch_bounds__(256) void gate7_k(
    const bf16* __restrict__ k2, const bf16* __restrict__ obj,
    bf16* __restrict__ rec7)
{
  size_t idx = (size_t)blockIdx.x * 256 + threadIdx.x;
  float ov = b2f(obj[idx]);
  rec7[idx] = f2b(b2f(k2[idx]) / (1.f + __expf(-ov)));
}

// ==================================================================
extern "C" void kernel_launch(void* const* d_in, const int* in_sizes, int n_in,
                              void* d_out, int out_size, void* d_ws, size_t ws_size,
                              hipStream_t stream)
{
  (void)hipGetLastError();  // clear stale errors

  static float h_sent[64];
  auto send_sentinel = [&](float val){
    for (int i = 0; i < 64; i++) h_sent[i] = val;
    hipMemcpyAsync(d_out, h_sent, 256, hipMemcpyHostToDevice, stream);
  };

  static const int EXP_SIZES[53] = {
    25690112, 32768, 100352, 1179648, 512, 512, 512, 196608, 768, 65536,
    256, 256, 256, 256, 256, 256, 256, 8388608, 32768, 64,
    64, 256, 256, 524288, 2048, 524288, 256, 589824, 2304, 196608,
    768, 768, 768, 768, 768, 1572864, 6144, 1572864, 768, 1179648,
    512, 512, 512, 1179648, 512, 512, 512, 1179648, 512, 589824,
    256, 256, 256 };
  if (n_in != 53){ send_sentinel(6600.f + (float)n_in); return; }
  for (int i = 0; i < 53; i++)
    if (in_sizes[i] != EXP_SIZES[i]){ send_sentinel(6000.f + 10.f*i); return; }
  if (out_size != 25690112){ send_sentinel(3000.f + (float)(out_size >> 20)); return; }
  if (ws_size < 77070400ull){ send_sentinel(2000.f + (float)(ws_size >> 20)); return; }

  const float* roi    = (const float*)d_in[0];
  const float* proF   = (const float*)d_in[1];
  const float* encW   = (const float*)d_in[3];
  const float* encB   = (const float*)d_in[4];
  const float* encG   = (const float*)d_in[5];
  const float* encBB  = (const float*)d_in[6];
  const float* aqkvW  = (const float*)d_in[7];
  const float* aqkvB  = (const float*)d_in[8];
  const float* aoutW  = (const float*)d_in[9];
  const float* aoutB  = (const float*)d_in[10];
  const float* n1g    = (const float*)d_in[11];
  const float* n1b    = (const float*)d_in[12];
  const float* n2g    = (const float*)d_in[13];
  const float* n2b    = (const float*)d_in[14];
  const float* n3g    = (const float*)d_in[15];
  const float* n3b    = (const float*)d_in[16];
  const float* dynW   = (const float*)d_in[17];
  const float* dynB   = (const float*)d_in[18];
  const float* dn1g   = (const float*)d_in[19];
  const float* dn1b   = (const float*)d_in[20];
  const float* dn2g   = (const float*)d_in[21];
  const float* dn2b   = (const float*)d_in[22];
  const float* lin1W  = (const float*)d_in[23];
  const float* lin1B  = (const float*)d_in[24];
  const float* lin2W  = (const float*)d_in[25];
  const float* lin2B  = (const float*)d_in[26];
  const float* teqkvW = (const float*)d_in[27];
  const float* teqkvB = (const float*)d_in[28];
  const float* teoutW = (const float*)d_in[29];
  const float* teoutB = (const float*)d_in[30];
  const float* teln1g = (const float*)d_in[31];
  const float* teln1b = (const float*)d_in[32];
  const float* teln2g = (const float*)d_in[33];
  const float* teln2b = (const float*)d_in[34];
  const float* teff1W = (const float*)d_in[35];
  const float* teff1B = (const float*)d_in[36];
  const float* teff2W = (const float*)d_in[37];
  const float* teff2B = (const float*)d_in[38];
  const float* recW   = (const float*)d_in[39];
  const float* recB   = (const float*)d_in[40];
  const float* recG   = (const float*)d_in[41];
  const float* recBB  = (const float*)d_in[42];
  const float* dAW    = (const float*)d_in[43];
  const float* dAB    = (const float*)d_in[44];
  const float* dAG    = (const float*)d_in[45];
  const float* dABB   = (const float*)d_in[46];
  const float* dBW    = (const float*)d_in[47];
  const float* dBB_   = (const float*)d_in[48];
  const float* dfW    = (const float*)d_in[49];
  const float* dfB    = (const float*)d_in[50];
  const float* dfG    = (const float*)d_in[51];
  const float* dfBB   = (const float*)d_in[52];

  // ---- workspace layout (bf16 elems). ws >= 77,070,400 bytes. ----
  bf16* base   = (bf16*)d_ws;
  bf16* wT     = base + 0;         //  5,308,416 (9 x 589,824), whole launch
  bf16* k1     = base + 5308416;   //  6,422,528  NHWC 14x14
  bf16* k2     = base + 11730944;  //  1,605,632  NHWC 7x7
  bf16* qkvP   = base + 13336576;  //     98,304
  bf16* attoP  = base + 13434880;  //     32,768
  bf16* mhaP   = base + 13467648;  //     32,768
  bf16* proQ   = base + 13500416;  //     32,768
  bf16* f1     = base + 13533184;  //    401,408
  bf16* obj0   = base + 13934592;  //  1,605,632
  bf16* tmp    = base + 15540224;  //  1,605,632
  bf16* atto   = base + 17145856;  //  1,605,632 (TE attn out; proB aliases early)
  bf16* obj    = base + 18751488;  //  1,605,632
  bf16* params = base + 20357120;  //  4,194,304 (dead after dyn_e2)
  bf16* rec7   = base + 20357120;  //  1,605,632 alias over params
  bf16* hbuf   = base + 24551424;  // 12,845,056 (FFN/TE only)
  bf16* qkvT   = base + 24551424;  //  4,816,896 alias over hbuf
  bf16* C14    = base + 24551424;  //  6,422,528 alias over hbuf
  bf16* B14    = base + 32112640;  //  6,422,528 (ends at byte 77,070,336)
  bf16* B28    = base + 5308416;   // 25,690,112 alias over k1..C14 (all dead)
  bf16* proB   = atto;             //     32,768 (dead before TE attn)
  // d_out (102.76 MB) as staged scratch, all dead before final fp32 write:
  bf16* roiT   = (bf16*)d_out;             // bytes 0..51,380,224 (dead after enc1)
  bf16* A14    = (bf16*)d_out;             // bytes 0..12,845,056 (decoder)
  bf16* C28    = (bf16*)d_out + 6422528;   // bytes 12.8M..64.2M (decoder)
  bf16* gw     = (bf16*)d_out + 26214400;  // bytes 52.4M..79.7M  bf16 GEMM weights
  bf16* gqkvW  = gw + 0;
  bf16* gaoutW = gw + 196608;
  bf16* gdynW  = gw + 262144;
  bf16* glin1W = gw + 8650752;
  bf16* glin2W = gw + 9175040;
  bf16* gteqkvW= gw + 9699328;
  bf16* gteoutW= gw + 10289152;
  bf16* gteff1W= gw + 10485760;
  bf16* gteff2W= gw + 12058624;
  float* score = (float*)((char*)d_ws + 77070336);  // 14-float scoreboard

  // ---- one-time layout transforms / dtype conversions ----
  auto cvt = [&](const float* s, bf16* d, int n){
    cvt_k<<<(n/4 + 255)/256, 256, 0, stream>>>(s, d, n/4);
  };
  troi_k<<<dim3(13,4,128),256,0,stream>>>(roi, roiT);
  wtrans_k<<<256,256,0,stream>>>(encW,            wT + 0*589824);
  wtrans_k<<<256,256,0,stream>>>(encW + 589824,   wT + 1*589824);
  wtrans_k<<<256,256,0,stream>>>(recW,            wT + 2*589824);
  wtrans_k<<<256,256,0,stream>>>(recW + 589824,   wT + 3*589824);
  wtrans_k<<<256,256,0,stream>>>(dAW,             wT + 4*589824);
  wtrans_k<<<256,256,0,stream>>>(dAW + 589824,    wT + 5*589824);
  wtrans_k<<<256,256,0,stream>>>(dBW,             wT + 6*589824);
  wtrans_k<<<256,256,0,stream>>>(dBW + 589824,    wT + 7*589824);
  wtrans_k<<<256,256,0,stream>>>(dfW,             wT + 8*589824);
  cvt(proF,   proB,    32768);
  cvt(aqkvW,  gqkvW,   196608);
  cvt(aoutW,  gaoutW,  65536);
  cvt(dynW,   gdynW,   8388608);
  cvt(lin1W,  glin1W,  524288);
  cvt(lin2W,  glin2W,  524288);
  cvt(teqkvW, gteqkvW, 589824);
  cvt(teoutW, gteoutW, 196608);
  cvt(teff1W, gteff1W, 1572864);
  cvt(teff2W, gteff2W, 1572864);
  probe_k<<<1,256,0,stream>>>(roiT, 25690112ull, score+0);

  // ---- k_encoder: 28 -> 14 -> 7 (NHWC) ----
  conv_mfma_k<14,14,28,28,0,2, 1,1,0,0,1,0><<<dim3(2,196),256,0,stream>>>(
      roiT, wT + 0*589824, encB, encG, encBB, nullptr, nullptr, k1);
  probe_k<<<1,256,0,stream>>>(k1, 6422528ull, score+1);
  conv_mfma_k<7,7,14,14,0,2, 1,1,0,0,1,0><<<dim3(2,49),256,0,stream>>>(
      k1, wT + 1*589824, encB+256, encG+256, encBB+256, nullptr, nullptr, k2);
  probe_k<<<1,256,0,stream>>>(k2, 1605632ull, score+2);

  // ---- self-attention over 128 query tokens ----
  gemm_mfma_k<0><<<dim3(6,1),256,0,stream>>>(proB, gqkvW, aqkvB, qkvP, 128,768,256);
  probe_k<<<1,256,0,stream>>>(qkvP, 98304ull, score+3);
  attn_k<128,8,32><<<dim3(8,2),64,0,stream>>>(qkvP, attoP);
  gemm_mfma_k<0><<<dim3(2,1),256,0,stream>>>(attoP, gaoutW, aoutB, mhaP, 128,256,256);
  add_ln_k<0,bf16><<<128,256,0,stream>>>(proB, mhaP, n1g, n1b, proQ);
  probe_k<<<1,256,0,stream>>>(proQ, 32768ull, score+4);

  // ---- DynamicConv ----
  gemm_mfma_k<0><<<dim3(256,1),256,0,stream>>>(proQ, gdynW, dynB, params, 128,32768,256);
  probe_k<<<1,256,0,stream>>>(params, 4194304ull, score+5);
  dyn_e1_k<<<128,256,0,stream>>>(k2, params, dn1g, dn1b, f1);
  probe_k<<<1,256,0,stream>>>(f1, 401408ull, score+6);
  dyn_e2_k<<<6272,256,0,stream>>>(k2, params, f1, dn2g, dn2b, n2g, n2b, obj0);
  probe_k<<<1,256,0,stream>>>(obj0, 1605632ull, score+7);

  // ---- FFN (ELU) + norm3 + PE ----
  gemm_mfma_k<2><<<dim3(16,49),256,0,stream>>>(obj0, glin1W, lin1B, hbuf, 6272,2048,256);
  gemm_mfma_k<0><<<dim3(2,49),256,0,stream>>>(hbuf, glin2W, lin2B, tmp, 6272,256,2048);
  add_ln_k<1,bf16><<<6272,256,0,stream>>>(obj0, tmp, n3g, n3b, obj);
  probe_k<<<1,256,0,stream>>>(obj, 1605632ull, score+8);

  // ---- 3-layer TransformerEncoder (post-norm, relu, nh=4) ----
  for (int l = 0; l < 3; l++){
    gemm_mfma_k<0><<<dim3(6,49),256,0,stream>>>(
        obj, gteqkvW + (size_t)l*196608, teqkvB + l*768, qkvT, 6272,768,256);
    attn_k<49,4,64><<<dim3(512,1),64,0,stream>>>(qkvT, atto);
    gemm_mfma_k<0><<<dim3(2,49),256,0,stream>>>(
        atto, gteoutW + (size_t)l*65536, teoutB + l*256, tmp, 6272,256,256);
    add_ln_k<0,bf16><<<6272,256,0,stream>>>(obj, tmp, teln1g + l*256, teln1b + l*256, obj);
    gemm_mfma_k<1><<<dim3(16,49),256,0,stream>>>(
        obj, gteff1W + (size_t)l*524288, teff1B + l*2048, hbuf, 6272,2048,256);
    gemm_mfma_k<0><<<dim3(2,49),256,0,stream>>>(
        hbuf, gteff2W + (size_t)l*524288, teff2B + l*256, tmp, 6272,256,2048);
    add_ln_k<0,bf16><<<6272,256,0,stream>>>(obj, tmp, teln2g + l*256, teln2b + l*256, obj);
  }
  probe_k<<<1,256,0,stream>>>(obj, 1605632ull, score+9);

  // ---- gated rec/det decoder pyramid (all NHWC) ----
  gate7_k<<<6272,256,0,stream>>>(k2, obj, rec7);
  probe_k<<<1,256,0,stream>>>(rec7, 1605632ull, score+10);
  // 7 -> 14
  conv_mfma_k<14,14,7,7,1,1, 1,1,1,0,1,0><<<dim3(2,196),256,0,stream>>>(
      rec7, wT + 2*589824, recB, recG, recBB, k1, nullptr, B14);
  probe_k<<<1,256,0,stream>>>(B14, 6422528ull, score+11);
  conv_mfma_k<14,14,7,7,1,1, 1,1,0,0,1,0><<<dim3(2,196),256,0,stream>>>(
      obj, wT + 4*589824, dAB, dAG, dABB, nullptr, nullptr, C14);
  conv_mfma_k<14,14,14,14,0,1, 0,0,1,1,1,0><<<dim3(2,196),256,0,stream>>>(
      C14, wT + 6*589824, dBB_, nullptr, nullptr, k1, B14, A14);
  probe_k<<<1,256,0,stream>>>(A14, 6422528ull, score+12);
  // 14 -> 28
  conv_mfma_k<28,28,14,14,1,1, 1,1,2,0,1,0><<<dim3(2,784),256,0,stream>>>(
      B14, wT + 3*589824, recB+256, recG+256, recBB+256, roi, nullptr, B28);
  probe_k<<<1,256,0,stream>>>(B28, 25690112ull, score+13);
  conv_mfma_k<28,28,14,14,1,1, 1,1,0,0,1,0><<<dim3(2,784),256,0,stream>>>(
      A14, wT + 5*589824, dAB+256, dAG+256, dABB+256, nullptr, nullptr, C28);
  conv_mfma_k<28,28,28,28,0,1, 0,0,2,1,0,0><<<dim3(2,784),256,0,stream>>>(
      C28, wT + 7*589824, dBB_+256, nullptr, nullptr, roi, B28, nullptr);
  // final conv + BN + ReLU, FP32 NHWC into d_out
  conv_mfma_k<28,28,28,28,0,1, 1,1,0,0,1,1><<<dim3(2,784),256,0,stream>>>(
      B28, wT + 8*589824, dfB, dfG, dfBB, nullptr, nullptr, d_out);

  // ---- verdict + launch-error readout ----
  verdict_k<<<1,64,0,stream>>>(score, 14, (float*)d_out);
  hipError_t le = hipGetLastError();
  if (le != hipSuccess){
    float v = 7000.f + 16.f * (float)(int)le;
    if (v > 60000.f) v = 60000.f;
    send_sentinel(v);
  }
}

// Round 4
// 2404.085 us; speedup vs baseline: 1.2164x; 1.0207x over previous
//
#include <hip/hip_runtime.h>
#include <hip/hip_bf16.h>
#include <string.h>

typedef __hip_bfloat16 bf16;
typedef short bf16x8 __attribute__((ext_vector_type(8)));
typedef float f32x16 __attribute__((ext_vector_type(16)));

typedef __attribute__((address_space(3))) unsigned int       as3_u32;
typedef const __attribute__((address_space(1))) unsigned int as1_u32c;

__device__ __forceinline__ void dma16(const void* g, void* l){
  __builtin_amdgcn_global_load_lds((as1_u32c*)g, (as3_u32*)l, 16, 0, 0);
}

// zeros for conv padding rows (device globals are zero-initialized).
// 1KB so sub*128B + swizzle offsets stay in-bounds.
__device__ __align__(256) unsigned char g_zpad[1024];

__device__ __forceinline__ float b2f(bf16 v){ return __bfloat162float(v); }
__device__ __forceinline__ bf16  f2b(float v){ return __float2bfloat16(v); }
__device__ __forceinline__ unsigned short f2bu(float v){
  union { bf16 b; unsigned short u; } x; x.b = __float2bfloat16(v); return x.u;
}
__device__ __forceinline__ float ldf(const float* p, size_t i){ return p[i]; }
__device__ __forceinline__ float ldf(const bf16*  p, size_t i){ return b2f(p[i]); }

// bijective XCD-aware block remap (m204): chunk-contiguous per XCD
__device__ __forceinline__ int xcd_swizzle(int lin, int nwg){
  int q = nwg >> 3, r = nwg & 7;
  int x = lin & 7, i = lin >> 3;
  int base = (x < r) ? x * (q + 1) : r * (q + 1) + (x - r) * q;
  return base + i;
}

// ------------------------------------------------------------------
// block-wide (256 thr) mean/var helper. sred must be float[4] shared.
// ------------------------------------------------------------------
__device__ __forceinline__ float2 block_stats256(float x, float* sred){
  float v = x;
  #pragma unroll
  for (int o = 32; o; o >>= 1) v += __shfl_xor(v, o);
  int w = threadIdx.x >> 6;
  if ((threadIdx.x & 63) == 0) sred[w] = v;
  __syncthreads();
  float mean = (sred[0] + sred[1] + sred[2] + sred[3]) * (1.f/256.f);
  __syncthreads();
  float d = x - mean;
  v = d * d;
  #pragma unroll
  for (int o = 32; o; o >>= 1) v += __shfl_xor(v, o);
  if ((threadIdx.x & 63) == 0) sred[w] = v;
  __syncthreads();
  float var = (sred[0] + sred[1] + sred[2] + sred[3]) * (1.f/256.f);
  __syncthreads();
  return make_float2(mean, var);
}

// ---- diagnostics ----
__global__ __launch_bounds__(256) void probe_k(const bf16* __restrict__ buf,
                                               unsigned long long len, float* score){
  __shared__ float sred[4];
  unsigned long long stride = len / 256ull; if (!stride) stride = 1;
  unsigned long long i = (unsigned long long)threadIdx.x * stride;
  if (i >= len) i = len - 1;
  float v = fabsf(b2f(buf[i]));
  #pragma unroll
  for (int o = 32; o; o >>= 1) v = fmaxf(v, __shfl_xor(v, o));
  if ((threadIdx.x & 63) == 0) sred[threadIdx.x >> 6] = v;
  __syncthreads();
  if (threadIdx.x == 0)
    score[0] = fmaxf(fmaxf(sred[0], sred[1]), fmaxf(sred[2], sred[3]));
}

__global__ void verdict_k(const float* score, int nstage, float* out){
  if (threadIdx.x == 0 && blockIdx.x == 0){
    for (int i = 0; i < nstage; i++){
      float s = score[i];
      if (!(s > 1e-8f)){
        float sent = 1000.f + 40.f * i;
        for (int j = 0; j < 64; j++) out[j] = sent;
        return;
      }
    }
  }
}

// ------------------------------------------------------------------
// fp32 -> bf16 bulk convert (n/4 float4s)
// ------------------------------------------------------------------
__global__ __launch_bounds__(256) void cvt_k(const float* __restrict__ s,
                                             bf16* __restrict__ d, int n4){
  int i = blockIdx.x * 256 + threadIdx.x;
  if (i < n4){
    float4 f = reinterpret_cast<const float4*>(s)[i];
    ushort4 u;
    u.x = f2bu(f.x); u.y = f2bu(f.y); u.z = f2bu(f.z); u.w = f2bu(f.w);
    reinterpret_cast<ushort4*>(d)[i] = u;
  }
}

// ------------------------------------------------------------------
// transpose roi (fp32 NCHW 28x28) -> bf16 NHWC
// ------------------------------------------------------------------
__global__ __launch_bounds__(256) void troi_k(const float* __restrict__ roi,
                                              bf16* __restrict__ o){
  __shared__ float tile[64][65];
  int n = blockIdx.z, c0 = blockIdx.y * 64, p0 = blockIdx.x * 64;
  int a = threadIdx.x & 63, bq = threadIdx.x >> 6;
  #pragma unroll
  for (int cs = bq; cs < 64; cs += 4){
    int p = p0 + a;
    tile[cs][a] = (p < 784) ? roi[((size_t)n*256 + c0 + cs)*784 + p] : 0.f;
  }
  __syncthreads();
  #pragma unroll
  for (int ps = bq; ps < 64; ps += 4){
    int p = p0 + ps;
    if (p < 784) o[((size_t)n*784 + p)*256 + c0 + a] = f2b(tile[a][ps]);
  }
}

// ------------------------------------------------------------------
// weight transpose: w[co][ci][tap] fp32 -> wT[co][tap*256+ci] bf16
// ------------------------------------------------------------------
__global__ __launch_bounds__(256) void wtrans_k(const float* __restrict__ w,
                                                bf16* __restrict__ o){
  int co = blockIdx.x, t = threadIdx.x;
  const float* wp = w + (size_t)co * 2304 + (size_t)t * 9;
  #pragma unroll
  for (int tap = 0; tap < 9; tap++)
    o[(size_t)co * 2304 + tap * 256 + t] = f2b(wp[tap]);
}

// ------------------------------------------------------------------
// MFMA tile compute (128x128 block tile, 4 waves of 64x64, K-step 64)
// LDS row = 64 bf16 = 128B; 16B chunks XOR-permuted by ((row&7)<<4).
// DMA writes LDS LINEARLY; the permutation is applied on the per-lane
// GLOBAL source address at stage time, and again at read time.
// ------------------------------------------------------------------
__device__ __forceinline__ void mfma_step64(const unsigned short* As,
                                            const unsigned short* Bs,
                                            int wr, int wc, int lane,
                                            f32x16 (&acc)[2][2]){
  const char* asb = (const char*)As;
  const char* bsb = (const char*)Bs;
  int l31 = lane & 31;
  int lsw = (l31 & 7) << 4;
  int hi  = (lane >> 5) << 4;
  #pragma unroll
  for (int kb = 0; kb < 4; kb++){
    int cb = (kb*32 + hi) ^ lsw;
    bf16x8 a0 = *reinterpret_cast<const bf16x8*>(asb + (wr      + l31)*128 + cb);
    bf16x8 a1 = *reinterpret_cast<const bf16x8*>(asb + (wr + 32 + l31)*128 + cb);
    bf16x8 b0 = *reinterpret_cast<const bf16x8*>(bsb + (wc      + l31)*128 + cb);
    bf16x8 b1 = *reinterpret_cast<const bf16x8*>(bsb + (wc + 32 + l31)*128 + cb);
    acc[0][0] = __builtin_amdgcn_mfma_f32_32x32x16_bf16(a0, b0, acc[0][0], 0, 0, 0);
    acc[0][1] = __builtin_amdgcn_mfma_f32_32x32x16_bf16(a0, b1, acc[0][1], 0, 0, 0);
    acc[1][0] = __builtin_amdgcn_mfma_f32_32x32x16_bf16(a1, b0, acc[1][0], 0, 0, 0);
    acc[1][1] = __builtin_amdgcn_mfma_f32_32x32x16_bf16(a1, b1, acc[1][1], 0, 0, 0);
  }
}

// ------------------------------------------------------------------
// MFMA NT GEMM: C[M,N] = act(A[M,K] @ W[N,K]^T + bias), all bf16 in.
// M%128==0, N%128==0, K%64==0.
// m97 structure: SINGLE 32KB LDS buffer, stage -> bar -> MFMA -> bar.
// Latency hiding comes from 3+ resident blocks/CU, not intra-block dbuf.
// ------------------------------------------------------------------
template<int ACT>
__global__ __launch_bounds__(256) void gemm_mfma_k(
    const bf16* __restrict__ A, const bf16* __restrict__ W,
    const float* __restrict__ bias, bf16* __restrict__ C,
    int M, int N, int K)
{
  __shared__ __align__(16) unsigned short As[8192];
  __shared__ __align__(16) unsigned short Bs[8192];
  int t = threadIdx.x;
  int nbx = gridDim.x;
  int lin = blockIdx.y * nbx + blockIdx.x;
  int wg  = xcd_swizzle(lin, nbx * gridDim.y);
  int n0 = (wg % nbx) * 128, m0 = (wg / nbx) * 128;
  int lane = t & 63, wave = t >> 6;
  int wr = (wave >> 1) * 64, wc = (wave & 1) * 64;
  int lrow = lane >> 3;                         // 0..7: row within 8-row DMA group
  int e0   = (((lane & 7) ^ lrow) << 3);        // src element offset (inverse swizzle)

  f32x16 acc[2][2];
  #pragma unroll
  for (int i = 0; i < 2; i++)
    #pragma unroll
    for (int j = 0; j < 2; j++)
      #pragma unroll
      for (int r = 0; r < 16; r++) acc[i][j][r] = 0.f;

  const bf16* apr[4]; const bf16* bpr[4];
  #pragma unroll
  for (int i = 0; i < 4; i++){
    int r = wave*32 + i*8 + lrow;
    apr[i] = A + (size_t)(m0 + r) * K + e0;
    bpr[i] = W + (size_t)(n0 + r) * K + e0;
  }

  int NIT = K >> 6;
  #pragma unroll 1
  for (int it = 0; it < NIT; ++it){
    #pragma unroll
    for (int i = 0; i < 4; i++){
      dma16(apr[i] + it*64, &As[(wave*32 + i*8) * 64]);
      dma16(bpr[i] + it*64, &Bs[(wave*32 + i*8) * 64]);
    }
    __syncthreads();
    mfma_step64(As, Bs, wr, wc, lane, acc);
    __syncthreads();
  }

  int l31 = lane & 31;
  int rbase = m0 + wr + ((lane >> 5) << 2);
  #pragma unroll
  for (int j = 0; j < 2; j++){
    int n = n0 + wc + j*32 + l31;
    float bv = bias ? bias[n] : 0.f;
    #pragma unroll
    for (int i = 0; i < 2; i++){
      #pragma unroll
      for (int r = 0; r < 16; r++){
        int row = rbase + i*32 + (r & 3) + ((r >> 2) << 3);
        float v = acc[i][j][r] + bv;
        if (ACT == 1) v = fmaxf(v, 0.f);
        if (ACT == 2) v = v > 0.f ? v : (__expf(v) - 1.f);
        C[(size_t)row * N + n] = f2b(v);
      }
    }
  }
}

// ------------------------------------------------------------------
// MFMA 3x3 conv, Cin=Cout=256, pad 1, NHWC bf16 in/out, batch=128.
// Implicit GEMM: rows = (n*HWo+p), cols = co, K=2304 (36 steps of 64).
// m97 structure (single 32KB LDS buffer, 2 barriers / K-step).
// Tap row-pointers recomputed only every 4th step (sub==0).
// RES_MODE: 0 none, 1 bf16 NHWC, 2 fp32 NCHW.
// ------------------------------------------------------------------
template<int Ho,int Wo,int Hi,int Wi,int UP2,int STRIDE,
         int HAS_BN,int RELU,int RES_MODE,int GATE,int WOUT,int OUTF>
__global__ __launch_bounds__(256) void conv_mfma_k(
    const bf16* __restrict__ in, const bf16* __restrict__ wTl,
    const float* __restrict__ cbias,
    const float* __restrict__ bng, const float* __restrict__ bnb,
    const void* __restrict__ res, bf16* __restrict__ gate,
    void* __restrict__ out)
{
  constexpr int HWo = Ho * Wo;
  constexpr int Hv = UP2 ? 2*Hi : Hi;
  constexpr int Wv = UP2 ? 2*Wi : Wi;
  __shared__ __align__(16) unsigned short As[8192];
  __shared__ __align__(16) unsigned short Bs[8192];
  int t = threadIdx.x;
  int nbx = gridDim.x;
  int lin = blockIdx.y * nbx + blockIdx.x;
  int wg  = xcd_swizzle(lin, nbx * gridDim.y);
  int co0 = (wg % nbx) * 128;
  int gp0 = (wg / nbx) * 128;
  int lane = t & 63, wave = t >> 6;
  int wr = (wave >> 1) * 64, wc = (wave & 1) * 64;
  int lrow = lane >> 3;
  int e0   = (((lane & 7) ^ lrow) << 3);

  // per-thread geometry of its 4 staged A-rows / B-rows
  int nA[4], oyA[4], oxA[4]; size_t wbase[4];
  #pragma unroll
  for (int i = 0; i < 4; i++){
    int r  = wave*32 + i*8 + lrow;
    int gp = gp0 + r;
    nA[i] = gp / HWo;
    int p = gp - nA[i] * HWo;
    oyA[i] = p / Wo; oxA[i] = p - oyA[i] * Wo;
    wbase[i] = (size_t)(co0 + r) * 2304 + e0;
  }

  f32x16 acc[2][2];
  #pragma unroll
  for (int i = 0; i < 2; i++)
    #pragma unroll
    for (int j = 0; j < 2; j++)
      #pragma unroll
      for (int r = 0; r < 16; r++) acc[i][j][r] = 0.f;

  const bf16* arp[4]; const bf16* brp[4];

  #pragma unroll 1
  for (int it = 0; it < 36; ++it){
    int tap = it >> 2, sub = it & 3;
    if (sub == 0){
      int ky = tap / 3, kx = tap - ky * 3;
      #pragma unroll
      for (int i = 0; i < 4; i++){
        int iy = oyA[i]*STRIDE + ky - 1;
        int ix = oxA[i]*STRIDE + kx - 1;
        bool val = (iy >= 0) && (iy < Hv) && (ix >= 0) && (ix < Wv);
        int sy = UP2 ? (iy >> 1) : iy;
        int sx = UP2 ? (ix >> 1) : ix;
        arp[i] = val
          ? in + (((size_t)nA[i] * Hi + sy) * Wi + sx) * 256 + e0
          : (const bf16*)g_zpad + e0;
        brp[i] = wTl + wbase[i] + tap*256;
      }
    }
    #pragma unroll
    for (int i = 0; i < 4; i++){
      dma16(arp[i] + sub*64, &As[(wave*32 + i*8) * 64]);
      dma16(brp[i] + sub*64, &Bs[(wave*32 + i*8) * 64]);
    }
    __syncthreads();
    mfma_step64(As, Bs, wr, wc, lane, acc);
    __syncthreads();
  }

  int l31 = lane & 31;
  int rbase = gp0 + wr + ((lane >> 5) << 2);
  #pragma unroll
  for (int j = 0; j < 2; j++){
    int co = co0 + wc + j*32 + l31;
    float cb = cbias[co];
    float scale = 1.f, shift = cb;
    if (HAS_BN){ float g = bng[co]; scale = g; shift = cb*g + bnb[co]; }
    #pragma unroll
    for (int i = 0; i < 2; i++){
      #pragma unroll
      for (int r = 0; r < 16; r++){
        int grow = rbase + i*32 + (r & 3) + ((r >> 2) << 3);
        float v = acc[i][j][r] * scale + shift;
        if (RELU) v = fmaxf(v, 0.f);
        size_t oidx = (size_t)grow * 256 + co;
        if (RES_MODE == 1) v += b2f(((const bf16*)res)[oidx]);
        if (RES_MODE == 2){
          int rn = grow / HWo, rp = grow - rn * HWo;
          v += ((const float*)res)[((size_t)rn * 256 + co) * HWo + rp];
        }
        if (GATE){
          float gv = b2f(gate[oidx]);
          gate[oidx] = f2b(gv / (1.f + __expf(-v)));
        }
        if (WOUT){
          if (OUTF) ((float*)out)[oidx] = v;
          else      ((bf16*)out)[oidx]  = f2b(v);
        }
      }
    }
  }
}

// ------------------------------------------------------------------
// MHA (online softmax). qkv rows (b*S+s), cols [q|k|v] each D=NH*DH.
// ------------------------------------------------------------------
template<int S, int NH, int DH>
__global__ __launch_bounds__(64) void attn_k(
    const bf16* __restrict__ qkv, bf16* __restrict__ out)
{
  const int D = NH * DH;
  int b = blockIdx.x / NH, h = blockIdx.x % NH;
  int chunk = blockIdx.y;
  int lane = threadIdx.x;
  __shared__ float ks[S][DH];
  __shared__ float vs[S][DH];
  __shared__ float os[64][DH];
  for (int idx = lane; idx < S*DH; idx += 64){
    int tt = idx / DH, d = idx % DH;
    size_t row = (size_t)(b*S + tt) * (3*D);
    ks[tt][d] = b2f(qkv[row +   D + h*DH + d]);
    vs[tt][d] = b2f(qkv[row + 2*D + h*DH + d]);
  }
  __syncthreads();
  int s = chunk*64 + lane;
  float q[DH];
  const float scale = 1.f / sqrtf((float)DH);
  if (s < S){
    size_t row = (size_t)(b*S + s) * (3*D);
    #pragma unroll
    for (int d = 0; d < DH; d++) q[d] = b2f(qkv[row + h*DH + d]) * scale;
  } else {
    #pragma unroll
    for (int d = 0; d < DH; d++) q[d] = 0.f;
  }
  float o[DH];
  #pragma unroll
  for (int d = 0; d < DH; d++) o[d] = 0.f;
  float m = -1e30f, l = 0.f;
  for (int tt = 0; tt < S; tt++){
    float sc = 0.f;
    #pragma unroll
    for (int d = 0; d < DH; d++) sc = fmaf(q[d], ks[tt][d], sc);
    float mn = fmaxf(m, sc);
    float corr = __expf(m - mn);
    float e = __expf(sc - mn);
    l = l * corr + e;
    #pragma unroll
    for (int d = 0; d < DH; d++) o[d] = fmaf(o[d], corr, e * vs[tt][d]);
    m = mn;
  }
  float inv = 1.f / l;
  #pragma unroll
  for (int d = 0; d < DH; d++) os[lane][d] = o[d] * inv;
  __syncthreads();
  for (int idx = lane; idx < 64*DH; idx += 64){
    int sl = idx / DH, d = idx % DH;
    int ss = chunk*64 + sl;
    if (ss < S) out[(size_t)(b*S + ss) * D + h*DH + d] = f2b(os[sl][d]);
  }
}

// ------------------------------------------------------------------
// out[r,:] = LN(a[r,:]+b[r,:]) * g + bb  (+ PE[r%49,:] if ADD_PE)
// ------------------------------------------------------------------
template<int ADD_PE, typename TA>
__global__ __launch_bounds__(256) void add_ln_k(
    const TA* __restrict__ a, const bf16* __restrict__ bsrc,
    const float* __restrict__ g, const float* __restrict__ bb, bf16* out)
{
  __shared__ float sred[4];
  int r = blockIdx.x, c = threadIdx.x;
  size_t idx = (size_t)r * 256 + c;
  float x = ldf(a, idx) + b2f(bsrc[idx]);
  float2 mv = block_stats256(x, sred);
  float y = (x - mv.x) * rsqrtf(mv.y + 1e-5f) * g[c] + bb[c];
  if (ADD_PE){
    int s = r % 49;
    float freq = __expf((float)(c & ~1) * (-9.210340371976184f / 256.f));
    float ang = (float)s * freq;
    y += (c & 1) ? cosf(ang) : sinf(ang);
  }
  out[idx] = f2b(y);
}

// ------------------------------------------------------------------
// DynamicConv stage 1: f1[n,s,d] = elu(LN_d(sum_c feats[n,s,c]*p1[n,c,d]))
// ------------------------------------------------------------------
__global__ __launch_bounds__(256) void dyn_e1_k(
    const bf16* __restrict__ k2, const bf16* __restrict__ params,
    const float* __restrict__ g, const float* __restrict__ bb,
    bf16* __restrict__ f1)
{
  int n = blockIdx.x;
  int w = threadIdx.x >> 6, d = threadIdx.x & 63;
  const bf16* pp = params + (size_t)n * 32768 + d;
  for (int s = w; s < 49; s += 4){
    const bf16* fp = k2 + ((size_t)n*49 + s) * 256;
    float acc = 0.f;
    #pragma unroll 4
    for (int c = 0; c < 256; c++)
      acc = fmaf(b2f(fp[c]), b2f(pp[c*64]), acc);
    float v = acc;
    #pragma unroll
    for (int o = 32; o; o >>= 1) v += __shfl_xor(v, o);
    float mean = v * (1.f/64.f);
    float dd = acc - mean;
    v = dd * dd;
    #pragma unroll
    for (int o = 32; o; o >>= 1) v += __shfl_xor(v, o);
    float var = v * (1.f/64.f);
    float y = dd * rsqrtf(var + 1e-5f) * g[d] + bb[d];
    y = y > 0.f ? y : (__expf(y) - 1.f);
    f1[((size_t)n*49 + s) * 64 + d] = f2b(y);
  }
}

// ------------------------------------------------------------------
// DynamicConv stage 2 + norm2 (k2 NHWC)
// ------------------------------------------------------------------
__global__ __launch_bounds__(256) void dyn_e2_k(
    const bf16* __restrict__ k2, const bf16* __restrict__ params,
    const bf16* __restrict__ f1,
    const float* __restrict__ g2, const float* __restrict__ bb2,
    const float* __restrict__ ng, const float* __restrict__ nb,
    bf16* __restrict__ obj0)
{
  __shared__ float sred[4];
  int ns = blockIdx.x; int n = ns / 49, s = ns % 49;
  int c = threadIdx.x;
  const bf16* pp  = params + (size_t)n * 32768 + 16384 + c;
  const bf16* f1p = f1 + (size_t)ns * 64;
  float acc = 0.f;
  #pragma unroll 8
  for (int d = 0; d < 64; d++)
    acc = fmaf(b2f(f1p[d]), b2f(pp[d*256]), acc);
  float2 mv = block_stats256(acc, sred);
  float y = (acc - mv.x) * rsqrtf(mv.y + 1e-5f) * g2[c] + bb2[c];
  y = y > 0.f ? y : (__expf(y) - 1.f);
  float pro2 = b2f(k2[((size_t)n*49 + s) * 256 + c]) + y;
  float2 mv2 = block_stats256(pro2, sred);
  float y2 = (pro2 - mv2.x) * rsqrtf(mv2.y + 1e-5f) * ng[c] + nb[c];
  obj0[(size_t)ns * 256 + c] = f2b(y2);
}

// ------------------------------------------------------------------
// gate at 7x7 (all NHWC): rec7 = k2 * sigmoid(obj)
// ------------------------------------------------------------------
__global__ __launch_bounds__(256) void gate7_k(
    const bf16* __restrict__ k2, const bf16* __restrict__ obj,
    bf16* __restrict__ rec7)
{
  size_t idx = (size_t)blockIdx.x * 256 + threadIdx.x;
  float ov = b2f(obj[idx]);
  rec7[idx] = f2b(b2f(k2[idx]) / (1.f + __expf(-ov)));
}

// ==================================================================
extern "C" void kernel_launch(void* const* d_in, const int* in_sizes, int n_in,
                              void* d_out, int out_size, void* d_ws, size_t ws_size,
                              hipStream_t stream)
{
  (void)hipGetLastError();  // clear stale errors

  static float h_sent[64];
  auto send_sentinel = [&](float val){
    for (int i = 0; i < 64; i++) h_sent[i] = val;
    hipMemcpyAsync(d_out, h_sent, 256, hipMemcpyHostToDevice, stream);
  };

  static const int EXP_SIZES[53] = {
    25690112, 32768, 100352, 1179648, 512, 512, 512, 196608, 768, 65536,
    256, 256, 256, 256, 256, 256, 256, 8388608, 32768, 64,
    64, 256, 256, 524288, 2048, 524288, 256, 589824, 2304, 196608,
    768, 768, 768, 768, 768, 1572864, 6144, 1572864, 768, 1179648,
    512, 512, 512, 1179648, 512, 512, 512, 1179648, 512, 589824,
    256, 256, 256 };
  if (n_in != 53){ send_sentinel(6600.f + (float)n_in); return; }
  for (int i = 0; i < 53; i++)
    if (in_sizes[i] != EXP_SIZES[i]){ send_sentinel(6000.f + 10.f*i); return; }
  if (out_size != 25690112){ send_sentinel(3000.f + (float)(out_size >> 20)); return; }
  if (ws_size < 77070400ull){ send_sentinel(2000.f + (float)(ws_size >> 20)); return; }

  const float* roi    = (const float*)d_in[0];
  const float* proF   = (const float*)d_in[1];
  const float* encW   = (const float*)d_in[3];
  const float* encB   = (const float*)d_in[4];
  const float* encG   = (const float*)d_in[5];
  const float* encBB  = (const float*)d_in[6];
  const float* aqkvW  = (const float*)d_in[7];
  const float* aqkvB  = (const float*)d_in[8];
  const float* aoutW  = (const float*)d_in[9];
  const float* aoutB  = (const float*)d_in[10];
  const float* n1g    = (const float*)d_in[11];
  const float* n1b    = (const float*)d_in[12];
  const float* n2g    = (const float*)d_in[13];
  const float* n2b    = (const float*)d_in[14];
  const float* n3g    = (const float*)d_in[15];
  const float* n3b    = (const float*)d_in[16];
  const float* dynW   = (const float*)d_in[17];
  const float* dynB   = (const float*)d_in[18];
  const float* dn1g   = (const float*)d_in[19];
  const float* dn1b   = (const float*)d_in[20];
  const float* dn2g   = (const float*)d_in[21];
  const float* dn2b   = (const float*)d_in[22];
  const float* lin1W  = (const float*)d_in[23];
  const float* lin1B  = (const float*)d_in[24];
  const float* lin2W  = (const float*)d_in[25];
  const float* lin2B  = (const float*)d_in[26];
  const float* teqkvW = (const float*)d_in[27];
  const float* teqkvB = (const float*)d_in[28];
  const float* teoutW = (const float*)d_in[29];
  const float* teoutB = (const float*)d_in[30];
  const float* teln1g = (const float*)d_in[31];
  const float* teln1b = (const float*)d_in[32];
  const float* teln2g = (const float*)d_in[33];
  const float* teln2b = (const float*)d_in[34];
  const float* teff1W = (const float*)d_in[35];
  const float* teff1B = (const float*)d_in[36];
  const float* teff2W = (const float*)d_in[37];
  const float* teff2B = (const float*)d_in[38];
  const float* recW   = (const float*)d_in[39];
  const float* recB   = (const float*)d_in[40];
  const float* recG   = (const float*)d_in[41];
  const float* recBB  = (const float*)d_in[42];
  const float* dAW    = (const float*)d_in[43];
  const float* dAB    = (const float*)d_in[44];
  const float* dAG    = (const float*)d_in[45];
  const float* dABB   = (const float*)d_in[46];
  const float* dBW    = (const float*)d_in[47];
  const float* dBB_   = (const float*)d_in[48];
  const float* dfW    = (const float*)d_in[49];
  const float* dfB    = (const float*)d_in[50];
  const float* dfG    = (const float*)d_in[51];
  const float* dfBB   = (const float*)d_in[52];

  // ---- workspace layout (bf16 elems). ws >= 77,070,400 bytes. ----
  bf16* base   = (bf16*)d_ws;
  bf16* wT     = base + 0;         //  5,308,416 (9 x 589,824), whole launch
  bf16* k1     = base + 5308416;   //  6,422,528  NHWC 14x14
  bf16* k2     = base + 11730944;  //  1,605,632  NHWC 7x7
  bf16* qkvP   = base + 13336576;  //     98,304
  bf16* attoP  = base + 13434880;  //     32,768
  bf16* mhaP   = base + 13467648;  //     32,768
  bf16* proQ   = base + 13500416;  //     32,768
  bf16* f1     = base + 13533184;  //    401,408
  bf16* obj0   = base + 13934592;  //  1,605,632
  bf16* tmp    = base + 15540224;  //  1,605,632
  bf16* atto   = base + 17145856;  //  1,605,632 (TE attn out; proB aliases early)
  bf16* obj    = base + 18751488;  //  1,605,632
  bf16* params = base + 20357120;  //  4,194,304 (dead after dyn_e2)
  bf16* rec7   = base + 20357120;  //  1,605,632 alias over params
  bf16* hbuf   = base + 24551424;  // 12,845,056 (FFN/TE only)
  bf16* qkvT   = base + 24551424;  //  4,816,896 alias over hbuf
  bf16* C14    = base + 24551424;  //  6,422,528 alias over hbuf
  bf16* B14    = base + 32112640;  //  6,422,528 (ends at byte 77,070,336)
  bf16* B28    = base + 5308416;   // 25,690,112 alias over k1..C14 (all dead)
  bf16* proB   = atto;             //     32,768 (dead before TE attn)
  // d_out (102.76 MB) as staged scratch, all dead before final fp32 write:
  bf16* roiT   = (bf16*)d_out;             // bytes 0..51,380,224 (dead after enc1)
  bf16* A14    = (bf16*)d_out;             // bytes 0..12,845,056 (decoder)
  bf16* C28    = (bf16*)d_out + 6422528;   // bytes 12.8M..64.2M (decoder)
  bf16* gw     = (bf16*)d_out + 26214400;  // bytes 52.4M..79.7M  bf16 GEMM weights
  bf16* gqkvW  = gw + 0;
  bf16* gaoutW = gw + 196608;
  bf16* gdynW  = gw + 262144;
  bf16* glin1W = gw + 8650752;
  bf16* glin2W = gw + 9175040;
  bf16* gteqkvW= gw + 9699328;
  bf16* gteoutW= gw + 10289152;
  bf16* gteff1W= gw + 10485760;
  bf16* gteff2W= gw + 12058624;
  float* score = (float*)((char*)d_ws + 77070336);  // 14-float scoreboard

  // ---- one-time layout transforms / dtype conversions ----
  auto cvt = [&](const float* s, bf16* d, int n){
    cvt_k<<<(n/4 + 255)/256, 256, 0, stream>>>(s, d, n/4);
  };
  troi_k<<<dim3(13,4,128),256,0,stream>>>(roi, roiT);
  wtrans_k<<<256,256,0,stream>>>(encW,            wT + 0*589824);
  wtrans_k<<<256,256,0,stream>>>(encW + 589824,   wT + 1*589824);
  wtrans_k<<<256,256,0,stream>>>(recW,            wT + 2*589824);
  wtrans_k<<<256,256,0,stream>>>(recW + 589824,   wT + 3*589824);
  wtrans_k<<<256,256,0,stream>>>(dAW,             wT + 4*589824);
  wtrans_k<<<256,256,0,stream>>>(dAW + 589824,    wT + 5*589824);
  wtrans_k<<<256,256,0,stream>>>(dBW,             wT + 6*589824);
  wtrans_k<<<256,256,0,stream>>>(dBW + 589824,    wT + 7*589824);
  wtrans_k<<<256,256,0,stream>>>(dfW,             wT + 8*589824);
  cvt(proF,   proB,    32768);
  cvt(aqkvW,  gqkvW,   196608);
  cvt(aoutW,  gaoutW,  65536);
  cvt(dynW,   gdynW,   8388608);
  cvt(lin1W,  glin1W,  524288);
  cvt(lin2W,  glin2W,  524288);
  cvt(teqkvW, gteqkvW, 589824);
  cvt(teoutW, gteoutW, 196608);
  cvt(teff1W, gteff1W, 1572864);
  cvt(teff2W, gteff2W, 1572864);
  probe_k<<<1,256,0,stream>>>(roiT, 25690112ull, score+0);

  // ---- k_encoder: 28 -> 14 -> 7 (NHWC) ----
  conv_mfma_k<14,14,28,28,0,2, 1,1,0,0,1,0><<<dim3(2,196),256,0,stream>>>(
      roiT, wT + 0*589824, encB, encG, encBB, nullptr, nullptr, k1);
  probe_k<<<1,256,0,stream>>>(k1, 6422528ull, score+1);
  conv_mfma_k<7,7,14,14,0,2, 1,1,0,0,1,0><<<dim3(2,49),256,0,stream>>>(
      k1, wT + 1*589824, encB+256, encG+256, encBB+256, nullptr, nullptr, k2);
  probe_k<<<1,256,0,stream>>>(k2, 1605632ull, score+2);

  // ---- self-attention over 128 query tokens ----
  gemm_mfma_k<0><<<dim3(6,1),256,0,stream>>>(proB, gqkvW, aqkvB, qkvP, 128,768,256);
  probe_k<<<1,256,0,stream>>>(qkvP, 98304ull, score+3);
  attn_k<128,8,32><<<dim3(8,2),64,0,stream>>>(qkvP, attoP);
  gemm_mfma_k<0><<<dim3(2,1),256,0,stream>>>(attoP, gaoutW, aoutB, mhaP, 128,256,256);
  add_ln_k<0,bf16><<<128,256,0,stream>>>(proB, mhaP, n1g, n1b, proQ);
  probe_k<<<1,256,0,stream>>>(proQ, 32768ull, score+4);

  // ---- DynamicConv ----
  gemm_mfma_k<0><<<dim3(256,1),256,0,stream>>>(proQ, gdynW, dynB, params, 128,32768,256);
  probe_k<<<1,256,0,stream>>>(params, 4194304ull, score+5);
  dyn_e1_k<<<128,256,0,stream>>>(k2, params, dn1g, dn1b, f1);
  probe_k<<<1,256,0,stream>>>(f1, 401408ull, score+6);
  dyn_e2_k<<<6272,256,0,stream>>>(k2, params, f1, dn2g, dn2b, n2g, n2b, obj0);
  probe_k<<<1,256,0,stream>>>(obj0, 1605632ull, score+7);

  // ---- FFN (ELU) + norm3 + PE ----
  gemm_mfma_k<2><<<dim3(16,49),256,0,stream>>>(obj0, glin1W, lin1B, hbuf, 6272,2048,256);
  gemm_mfma_k<0><<<dim3(2,49),256,0,stream>>>(hbuf, glin2W, lin2B, tmp, 6272,256,2048);
  add_ln_k<1,bf16><<<6272,256,0,stream>>>(obj0, tmp, n3g, n3b, obj);
  probe_k<<<1,256,0,stream>>>(obj, 1605632ull, score+8);

  // ---- 3-layer TransformerEncoder (post-norm, relu, nh=4) ----
  for (int l = 0; l < 3; l++){
    gemm_mfma_k<0><<<dim3(6,49),256,0,stream>>>(
        obj, gteqkvW + (size_t)l*196608, teqkvB + l*768, qkvT, 6272,768,256);
    attn_k<49,4,64><<<dim3(512,1),64,0,stream>>>(qkvT, atto);
    gemm_mfma_k<0><<<dim3(2,49),256,0,stream>>>(
        atto, gteoutW + (size_t)l*65536, teoutB + l*256, tmp, 6272,256,256);
    add_ln_k<0,bf16><<<6272,256,0,stream>>>(obj, tmp, teln1g + l*256, teln1b + l*256, obj);
    gemm_mfma_k<1><<<dim3(16,49),256,0,stream>>>(
        obj, gteff1W + (size_t)l*524288, teff1B + l*2048, hbuf, 6272,2048,256);
    gemm_mfma_k<0><<<dim3(2,49),256,0,stream>>>(
        hbuf, gteff2W + (size_t)l*524288, teff2B + l*256, tmp, 6272,256,2048);
    add_ln_k<0,bf16><<<6272,256,0,stream>>>(obj, tmp, teln2g + l*256, teln2b + l*256, obj);
  }
  probe_k<<<1,256,0,stream>>>(obj, 1605632ull, score+9);

  // ---- gated rec/det decoder pyramid (all NHWC) ----
  gate7_k<<<6272,256,0,stream>>>(k2, obj, rec7);
  probe_k<<<1,256,0,stream>>>(rec7, 1605632ull, score+10);
  // 7 -> 14
  conv_mfma_k<14,14,7,7,1,1, 1,1,1,0,1,0><<<dim3(2,196),256,0,stream>>>(
      rec7, wT + 2*589824, recB, recG, recBB, k1, nullptr, B14);
  probe_k<<<1,256,0,stream>>>(B14, 6422528ull, score+11);
  conv_mfma_k<14,14,7,7,1,1, 1,1,0,0,1,0><<<dim3(2,196),256,0,stream>>>(
      obj, wT + 4*589824, dAB, dAG, dABB, nullptr, nullptr, C14);
  conv_mfma_k<14,14,14,14,0,1, 0,0,1,1,1,0><<<dim3(2,196),256,0,stream>>>(
      C14, wT + 6*589824, dBB_, nullptr, nullptr, k1, B14, A14);
  probe_k<<<1,256,0,stream>>>(A14, 6422528ull, score+12);
  // 14 -> 28
  conv_mfma_k<28,28,14,14,1,1, 1,1,2,0,1,0><<<dim3(2,784),256,0,stream>>>(
      B14, wT + 3*589824, recB+256, recG+256, recBB+256, roi, nullptr, B28);
  probe_k<<<1,256,0,stream>>>(B28, 25690112ull, score+13);
  conv_mfma_k<28,28,14,14,1,1, 1,1,0,0,1,0><<<dim3(2,784),256,0,stream>>>(
      A14, wT + 5*589824, dAB+256, dAG+256, dABB+256, nullptr, nullptr, C28);
  conv_mfma_k<28,28,28,28,0,1, 0,0,2,1,0,0><<<dim3(2,784),256,0,stream>>>(
      C28, wT + 7*589824, dBB_+256, nullptr, nullptr, roi, B28, nullptr);
  // final conv + BN + ReLU, FP32 NHWC into d_out
  conv_mfma_k<28,28,28,28,0,1, 1,1,0,0,1,1><<<dim3(2,784),256,0,stream>>>(
      B28, wT + 8*589824, dfB, dfG, dfBB, nullptr, nullptr, d_out);

  // ---- verdict + launch-error readout ----
  verdict_k<<<1,64,0,stream>>>(score, 14, (float*)d_out);
  hipError_t le = hipGetLastError();
  if (le != hipSuccess){
    float v = 7000.f + 16.f * (float)(int)le;
    if (v > 60000.f) v = 60000.f;
    send_sentinel(v);
  }
}

// Round 5
// 2188.755 us; speedup vs baseline: 1.3360x; 1.0984x over previous
//
#include <hip/hip_runtime.h>
#include <hip/hip_bf16.h>
#include <string.h>

typedef __hip_bfloat16 bf16;
typedef short bf16x8 __attribute__((ext_vector_type(8)));
typedef float f32x16 __attribute__((ext_vector_type(16)));

typedef __attribute__((address_space(3))) unsigned int       as3_u32;
typedef const __attribute__((address_space(1))) unsigned int as1_u32c;

__device__ __forceinline__ void dma16(const void* g, void* l){
  __builtin_amdgcn_global_load_lds((as1_u32c*)g, (as3_u32*)l, 16, 0, 0);
}

// zeros for conv padding rows (device globals are zero-initialized).
__device__ __align__(256) unsigned char g_zpad[1024];

__device__ __forceinline__ float b2f(bf16 v){ return __bfloat162float(v); }
__device__ __forceinline__ bf16  f2b(float v){ return __float2bfloat16(v); }
__device__ __forceinline__ unsigned short f2bu(float v){
  union { bf16 b; unsigned short u; } x; x.b = __float2bfloat16(v); return x.u;
}
__device__ __forceinline__ float ldf(const float* p, size_t i){ return p[i]; }
__device__ __forceinline__ float ldf(const bf16*  p, size_t i){ return b2f(p[i]); }

// bijective XCD-aware block remap (m204): chunk-contiguous per XCD
__device__ __forceinline__ int xcd_swizzle(int lin, int nwg){
  int q = nwg >> 3, r = nwg & 7;
  int x = lin & 7, i = lin >> 3;
  int base = (x < r) ? x * (q + 1) : r * (q + 1) + (x - r) * q;
  return base + i;
}

// ------------------------------------------------------------------
// block-wide (256 thr) mean/var helper. sred must be float[4] shared.
// ------------------------------------------------------------------
__device__ __forceinline__ float2 block_stats256(float x, float* sred){
  float v = x;
  #pragma unroll
  for (int o = 32; o; o >>= 1) v += __shfl_xor(v, o);
  int w = threadIdx.x >> 6;
  if ((threadIdx.x & 63) == 0) sred[w] = v;
  __syncthreads();
  float mean = (sred[0] + sred[1] + sred[2] + sred[3]) * (1.f/256.f);
  __syncthreads();
  float d = x - mean;
  v = d * d;
  #pragma unroll
  for (int o = 32; o; o >>= 1) v += __shfl_xor(v, o);
  if ((threadIdx.x & 63) == 0) sred[w] = v;
  __syncthreads();
  float var = (sred[0] + sred[1] + sred[2] + sred[3]) * (1.f/256.f);
  __syncthreads();
  return make_float2(mean, var);
}

// ---- diagnostics ----
__global__ __launch_bounds__(256) void probe_k(const bf16* __restrict__ buf,
                                               unsigned long long len, float* score){
  __shared__ float sred[4];
  unsigned long long stride = len / 256ull; if (!stride) stride = 1;
  unsigned long long i = (unsigned long long)threadIdx.x * stride;
  if (i >= len) i = len - 1;
  float v = fabsf(b2f(buf[i]));
  #pragma unroll
  for (int o = 32; o; o >>= 1) v = fmaxf(v, __shfl_xor(v, o));
  if ((threadIdx.x & 63) == 0) sred[threadIdx.x >> 6] = v;
  __syncthreads();
  if (threadIdx.x == 0)
    score[0] = fmaxf(fmaxf(sred[0], sred[1]), fmaxf(sred[2], sred[3]));
}

__global__ void verdict_k(const float* score, int nstage, float* out){
  if (threadIdx.x == 0 && blockIdx.x == 0){
    for (int i = 0; i < nstage; i++){
      float s = score[i];
      if (!(s > 1e-8f)){
        float sent = 1000.f + 40.f * i;
        for (int j = 0; j < 64; j++) out[j] = sent;
        return;
      }
    }
  }
}

// ------------------------------------------------------------------
// fp32 -> bf16 bulk convert (n/4 float4s)
// ------------------------------------------------------------------
__global__ __launch_bounds__(256) void cvt_k(const float* __restrict__ s,
                                             bf16* __restrict__ d, int n4){
  int i = blockIdx.x * 256 + threadIdx.x;
  if (i < n4){
    float4 f = reinterpret_cast<const float4*>(s)[i];
    ushort4 u;
    u.x = f2bu(f.x); u.y = f2bu(f.y); u.z = f2bu(f.z); u.w = f2bu(f.w);
    reinterpret_cast<ushort4*>(d)[i] = u;
  }
}

// ------------------------------------------------------------------
// transpose roi (fp32 NCHW 28x28) -> bf16 NHWC
// ------------------------------------------------------------------
__global__ __launch_bounds__(256) void troi_k(const float* __restrict__ roi,
                                              bf16* __restrict__ o){
  __shared__ float tile[64][65];
  int n = blockIdx.z, c0 = blockIdx.y * 64, p0 = blockIdx.x * 64;
  int a = threadIdx.x & 63, bq = threadIdx.x >> 6;
  #pragma unroll
  for (int cs = bq; cs < 64; cs += 4){
    int p = p0 + a;
    tile[cs][a] = (p < 784) ? roi[((size_t)n*256 + c0 + cs)*784 + p] : 0.f;
  }
  __syncthreads();
  #pragma unroll
  for (int ps = bq; ps < 64; ps += 4){
    int p = p0 + ps;
    if (p < 784) o[((size_t)n*784 + p)*256 + c0 + a] = f2b(tile[a][ps]);
  }
}

// ------------------------------------------------------------------
// weight transpose: w[co][ci][tap] fp32 -> wT[co][tap*256+ci] bf16
// ------------------------------------------------------------------
__global__ __launch_bounds__(256) void wtrans_k(const float* __restrict__ w,
                                                bf16* __restrict__ o){
  int co = blockIdx.x, t = threadIdx.x;
  const float* wp = w + (size_t)co * 2304 + (size_t)t * 9;
  #pragma unroll
  for (int tap = 0; tap < 9; tap++)
    o[(size_t)co * 2304 + tap * 256 + t] = f2b(wp[tap]);
}

// ------------------------------------------------------------------
// MFMA tile compute (128x128 block tile, 4 waves of 64x64, K-step 64)
// LDS row = 64 bf16 = 128B; 16B chunks XOR-permuted by ((row&7)<<4).
// DMA writes LDS LINEARLY; the permutation is applied on the per-lane
// GLOBAL source address at stage time, and again at read time.
// ------------------------------------------------------------------
__device__ __forceinline__ void mfma_step64(const unsigned short* As,
                                            const unsigned short* Bs,
                                            int wr, int wc, int lane,
                                            f32x16 (&acc)[2][2]){
  const char* asb = (const char*)As;
  const char* bsb = (const char*)Bs;
  int l31 = lane & 31;
  int lsw = (l31 & 7) << 4;
  int hi  = (lane >> 5) << 4;
  #pragma unroll
  for (int kb = 0; kb < 4; kb++){
    int cb = (kb*32 + hi) ^ lsw;
    bf16x8 a0 = *reinterpret_cast<const bf16x8*>(asb + (wr      + l31)*128 + cb);
    bf16x8 a1 = *reinterpret_cast<const bf16x8*>(asb + (wr + 32 + l31)*128 + cb);
    bf16x8 b0 = *reinterpret_cast<const bf16x8*>(bsb + (wc      + l31)*128 + cb);
    bf16x8 b1 = *reinterpret_cast<const bf16x8*>(bsb + (wc + 32 + l31)*128 + cb);
    acc[0][0] = __builtin_amdgcn_mfma_f32_32x32x16_bf16(a0, b0, acc[0][0], 0, 0, 0);
    acc[0][1] = __builtin_amdgcn_mfma_f32_32x32x16_bf16(a0, b1, acc[0][1], 0, 0, 0);
    acc[1][0] = __builtin_amdgcn_mfma_f32_32x32x16_bf16(a1, b0, acc[1][0], 0, 0, 0);
    acc[1][1] = __builtin_amdgcn_mfma_f32_32x32x16_bf16(a1, b1, acc[1][1], 0, 0, 0);
  }
}

// ------------------------------------------------------------------
// MFMA NT GEMM: C[M,N] = act(A[M,K] @ W[N,K]^T + bias), all bf16 in.
// M%128==0, N%128==0, K%64==0.
// DMA + LDS double-buffer, ONE barrier per K-step, placed AFTER the
// compute so prefetch DMAs overlap the MFMA phase (T14 issue-early).
// ------------------------------------------------------------------
template<int ACT>
__global__ __launch_bounds__(256) void gemm_mfma_k(
    const bf16* __restrict__ A, const bf16* __restrict__ W,
    const float* __restrict__ bias, bf16* __restrict__ C,
    int M, int N, int K)
{
  __shared__ __align__(16) unsigned short As[2][8192];
  __shared__ __align__(16) unsigned short Bs[2][8192];
  int t = threadIdx.x;
  int nbx = gridDim.x;
  int lin = blockIdx.y * nbx + blockIdx.x;
  int wg  = xcd_swizzle(lin, nbx * gridDim.y);
  int n0 = (wg % nbx) * 128, m0 = (wg / nbx) * 128;
  int lane = t & 63, wave = t >> 6;
  int wr = (wave >> 1) * 64, wc = (wave & 1) * 64;
  int lrow = lane >> 3;                         // 0..7: row within 8-row DMA group
  int e0   = (((lane & 7) ^ lrow) << 3);        // src element offset (inverse swizzle)

  f32x16 acc[2][2];
  #pragma unroll
  for (int i = 0; i < 2; i++)
    #pragma unroll
    for (int j = 0; j < 2; j++)
      #pragma unroll
      for (int r = 0; r < 16; r++) acc[i][j][r] = 0.f;

  const bf16* apr[4]; const bf16* bpr[4];
  #pragma unroll
  for (int i = 0; i < 4; i++){
    int r = wave*32 + i*8 + lrow;
    apr[i] = A + (size_t)(m0 + r) * K + e0;
    bpr[i] = W + (size_t)(n0 + r) * K + e0;
  }

  auto stage = [&](int buf, int k0){
    #pragma unroll
    for (int i = 0; i < 4; i++){
      dma16(apr[i] + k0, &As[buf][(wave*32 + i*8) * 64]);
      dma16(bpr[i] + k0, &Bs[buf][(wave*32 + i*8) * 64]);
    }
  };

  int NIT = K >> 6;
  stage(0, 0);
  __syncthreads();
  #pragma unroll 1
  for (int it = 0; it < NIT; ++it){
    if (it + 1 < NIT) stage((it+1)&1, (it+1)*64);   // issue early
    mfma_step64(As[it&1], Bs[it&1], wr, wc, lane, acc);
    __syncthreads();                               // wait late (drains prefetch)
  }

  int l31 = lane & 31;
  int rbase = m0 + wr + ((lane >> 5) << 2);
  #pragma unroll
  for (int j = 0; j < 2; j++){
    int n = n0 + wc + j*32 + l31;
    float bv = bias ? bias[n] : 0.f;
    #pragma unroll
    for (int i = 0; i < 2; i++){
      #pragma unroll
      for (int r = 0; r < 16; r++){
        int row = rbase + i*32 + (r & 3) + ((r >> 2) << 3);
        float v = acc[i][j][r] + bv;
        if (ACT == 1) v = fmaxf(v, 0.f);
        if (ACT == 2) v = v > 0.f ? v : (__expf(v) - 1.f);
        C[(size_t)row * N + n] = f2b(v);
      }
    }
  }
}

// ------------------------------------------------------------------
// MFMA 3x3 conv, Cin=Cout=256, pad 1, NHWC bf16 in/out, batch=128.
// Implicit GEMM: rows = (n*HWo+p), cols = co, K=2304 (36 steps of 64).
// DMA + LDS double-buffer, one barrier per K-step (issue-early/wait-late).
// RES_MODE: 0 none, 1 bf16 NHWC, 2 fp32 NCHW.
// ------------------------------------------------------------------
template<int Ho,int Wo,int Hi,int Wi,int UP2,int STRIDE,
         int HAS_BN,int RELU,int RES_MODE,int GATE,int WOUT,int OUTF>
__global__ __launch_bounds__(256) void conv_mfma_k(
    const bf16* __restrict__ in, const bf16* __restrict__ wTl,
    const float* __restrict__ cbias,
    const float* __restrict__ bng, const float* __restrict__ bnb,
    const void* __restrict__ res, bf16* __restrict__ gate,
    void* __restrict__ out)
{
  constexpr int HWo = Ho * Wo;
  constexpr int Hv = UP2 ? 2*Hi : Hi;
  constexpr int Wv = UP2 ? 2*Wi : Wi;
  __shared__ __align__(16) unsigned short As[2][8192];
  __shared__ __align__(16) unsigned short Bs[2][8192];
  int t = threadIdx.x;
  int nbx = gridDim.x;
  int lin = blockIdx.y * nbx + blockIdx.x;
  int wg  = xcd_swizzle(lin, nbx * gridDim.y);
  int co0 = (wg % nbx) * 128;
  int gp0 = (wg / nbx) * 128;
  int lane = t & 63, wave = t >> 6;
  int wr = (wave >> 1) * 64, wc = (wave & 1) * 64;
  int lrow = lane >> 3;
  int e0   = (((lane & 7) ^ lrow) << 3);

  // per-thread geometry of its 4 staged A-rows / B-rows
  int nA[4], oyA[4], oxA[4]; size_t wbase[4];
  #pragma unroll
  for (int i = 0; i < 4; i++){
    int r  = wave*32 + i*8 + lrow;
    int gp = gp0 + r;
    nA[i] = gp / HWo;
    int p = gp - nA[i] * HWo;
    oyA[i] = p / Wo; oxA[i] = p - oyA[i] * Wo;
    wbase[i] = (size_t)(co0 + r) * 2304 + e0;
  }

  f32x16 acc[2][2];
  #pragma unroll
  for (int i = 0; i < 2; i++)
    #pragma unroll
    for (int j = 0; j < 2; j++)
      #pragma unroll
      for (int r = 0; r < 16; r++) acc[i][j][r] = 0.f;

  const bf16* arp[4]; const bf16* brp[4];

  auto stage = [&](int buf, int it){
    int tap = it >> 2, sub = it & 3;
    if (sub == 0){
      int ky = tap / 3, kx = tap - ky * 3;
      #pragma unroll
      for (int i = 0; i < 4; i++){
        int iy = oyA[i]*STRIDE + ky - 1;
        int ix = oxA[i]*STRIDE + kx - 1;
        bool val = (iy >= 0) && (iy < Hv) && (ix >= 0) && (ix < Wv);
        int sy = UP2 ? (iy >> 1) : iy;
        int sx = UP2 ? (ix >> 1) : ix;
        arp[i] = val
          ? in + (((size_t)nA[i] * Hi + sy) * Wi + sx) * 256 + e0
          : (const bf16*)g_zpad + e0;
        brp[i] = wTl + wbase[i] + tap*256;
      }
    }
    #pragma unroll
    for (int i = 0; i < 4; i++){
      dma16(arp[i] + sub*64, &As[buf][(wave*32 + i*8) * 64]);
      dma16(brp[i] + sub*64, &Bs[buf][(wave*32 + i*8) * 64]);
    }
  };

  stage(0, 0);
  __syncthreads();
  #pragma unroll 1
  for (int it = 0; it < 36; ++it){
    if (it + 1 < 36) stage((it+1)&1, it+1);       // issue early
    mfma_step64(As[it&1], Bs[it&1], wr, wc, lane, acc);
    __syncthreads();                              // wait late
  }

  int l31 = lane & 31;
  int rbase = gp0 + wr + ((lane >> 5) << 2);
  #pragma unroll
  for (int j = 0; j < 2; j++){
    int co = co0 + wc + j*32 + l31;
    float cb = cbias[co];
    float scale = 1.f, shift = cb;
    if (HAS_BN){ float g = bng[co]; scale = g; shift = cb*g + bnb[co]; }
    #pragma unroll
    for (int i = 0; i < 2; i++){
      #pragma unroll
      for (int r = 0; r < 16; r++){
        int grow = rbase + i*32 + (r & 3) + ((r >> 2) << 3);
        float v = acc[i][j][r] * scale + shift;
        if (RELU) v = fmaxf(v, 0.f);
        size_t oidx = (size_t)grow * 256 + co;
        if (RES_MODE == 1) v += b2f(((const bf16*)res)[oidx]);
        if (RES_MODE == 2){
          int rn = grow / HWo, rp = grow - rn * HWo;
          v += ((const float*)res)[((size_t)rn * 256 + co) * HWo + rp];
        }
        if (GATE){
          float gv = b2f(gate[oidx]);
          gate[oidx] = f2b(gv / (1.f + __expf(-v)));
        }
        if (WOUT){
          if (OUTF) ((float*)out)[oidx] = v;
          else      ((bf16*)out)[oidx]  = f2b(v);
        }
      }
    }
  }
}

// ------------------------------------------------------------------
// MHA (online softmax). qkv rows (b*S+s), cols [q|k|v] each D=NH*DH.
// ------------------------------------------------------------------
template<int S, int NH, int DH>
__global__ __launch_bounds__(64) void attn_k(
    const bf16* __restrict__ qkv, bf16* __restrict__ out)
{
  const int D = NH * DH;
  int b = blockIdx.x / NH, h = blockIdx.x % NH;
  int chunk = blockIdx.y;
  int lane = threadIdx.x;
  __shared__ float ks[S][DH];
  __shared__ float vs[S][DH];
  __shared__ float os[64][DH];
  for (int idx = lane; idx < S*DH; idx += 64){
    int tt = idx / DH, d = idx % DH;
    size_t row = (size_t)(b*S + tt) * (3*D);
    ks[tt][d] = b2f(qkv[row +   D + h*DH + d]);
    vs[tt][d] = b2f(qkv[row + 2*D + h*DH + d]);
  }
  __syncthreads();
  int s = chunk*64 + lane;
  float q[DH];
  const float scale = 1.f / sqrtf((float)DH);
  if (s < S){
    size_t row = (size_t)(b*S + s) * (3*D);
    #pragma unroll
    for (int d = 0; d < DH; d++) q[d] = b2f(qkv[row + h*DH + d]) * scale;
  } else {
    #pragma unroll
    for (int d = 0; d < DH; d++) q[d] = 0.f;
  }
  float o[DH];
  #pragma unroll
  for (int d = 0; d < DH; d++) o[d] = 0.f;
  float m = -1e30f, l = 0.f;
  for (int tt = 0; tt < S; tt++){
    float sc = 0.f;
    #pragma unroll
    for (int d = 0; d < DH; d++) sc = fmaf(q[d], ks[tt][d], sc);
    float mn = fmaxf(m, sc);
    float corr = __expf(m - mn);
    float e = __expf(sc - mn);
    l = l * corr + e;
    #pragma unroll
    for (int d = 0; d < DH; d++) o[d] = fmaf(o[d], corr, e * vs[tt][d]);
    m = mn;
  }
  float inv = 1.f / l;
  #pragma unroll
  for (int d = 0; d < DH; d++) os[lane][d] = o[d] * inv;
  __syncthreads();
  for (int idx = lane; idx < 64*DH; idx += 64){
    int sl = idx / DH, d = idx % DH;
    int ss = chunk*64 + sl;
    if (ss < S) out[(size_t)(b*S + ss) * D + h*DH + d] = f2b(os[sl][d]);
  }
}

// ------------------------------------------------------------------
// out[r,:] = LN(a[r,:]+b[r,:]) * g + bb  (+ PE[r%49,:] if ADD_PE)
// ------------------------------------------------------------------
template<int ADD_PE, typename TA>
__global__ __launch_bounds__(256) void add_ln_k(
    const TA* __restrict__ a, const bf16* __restrict__ bsrc,
    const float* __restrict__ g, const float* __restrict__ bb, bf16* out)
{
  __shared__ float sred[4];
  int r = blockIdx.x, c = threadIdx.x;
  size_t idx = (size_t)r * 256 + c;
  float x = ldf(a, idx) + b2f(bsrc[idx]);
  float2 mv = block_stats256(x, sred);
  float y = (x - mv.x) * rsqrtf(mv.y + 1e-5f) * g[c] + bb[c];
  if (ADD_PE){
    int s = r % 49;
    float freq = __expf((float)(c & ~1) * (-9.210340371976184f / 256.f));
    float ang = (float)s * freq;
    y += (c & 1) ? cosf(ang) : sinf(ang);
  }
  out[idx] = f2b(y);
}

// ------------------------------------------------------------------
// DynamicConv stage 1: f1[n,s,d] = elu(LN_d(sum_c feats[n,s,c]*p1[n,c,d]))
// ------------------------------------------------------------------
__global__ __launch_bounds__(256) void dyn_e1_k(
    const bf16* __restrict__ k2, const bf16* __restrict__ params,
    const float* __restrict__ g, const float* __restrict__ bb,
    bf16* __restrict__ f1)
{
  int n = blockIdx.x;
  int w = threadIdx.x >> 6, d = threadIdx.x & 63;
  const bf16* pp = params + (size_t)n * 32768 + d;
  for (int s = w; s < 49; s += 4){
    const bf16* fp = k2 + ((size_t)n*49 + s) * 256;
    float acc = 0.f;
    #pragma unroll 4
    for (int c = 0; c < 256; c++)
      acc = fmaf(b2f(fp[c]), b2f(pp[c*64]), acc);
    float v = acc;
    #pragma unroll
    for (int o = 32; o; o >>= 1) v += __shfl_xor(v, o);
    float mean = v * (1.f/64.f);
    float dd = acc - mean;
    v = dd * dd;
    #pragma unroll
    for (int o = 32; o; o >>= 1) v += __shfl_xor(v, o);
    float var = v * (1.f/64.f);
    float y = dd * rsqrtf(var + 1e-5f) * g[d] + bb[d];
    y = y > 0.f ? y : (__expf(y) - 1.f);
    f1[((size_t)n*49 + s) * 64 + d] = f2b(y);
  }
}

// ------------------------------------------------------------------
// DynamicConv stage 2 + norm2 (k2 NHWC)
// ------------------------------------------------------------------
__global__ __launch_bounds__(256) void dyn_e2_k(
    const bf16* __restrict__ k2, const bf16* __restrict__ params,
    const bf16* __restrict__ f1,
    const float* __restrict__ g2, const float* __restrict__ bb2,
    const float* __restrict__ ng, const float* __restrict__ nb,
    bf16* __restrict__ obj0)
{
  __shared__ float sred[4];
  int ns = blockIdx.x; int n = ns / 49, s = ns % 49;
  int c = threadIdx.x;
  const bf16* pp  = params + (size_t)n * 32768 + 16384 + c;
  const bf16* f1p = f1 + (size_t)ns * 64;
  float acc = 0.f;
  #pragma unroll 8
  for (int d = 0; d < 64; d++)
    acc = fmaf(b2f(f1p[d]), b2f(pp[d*256]), acc);
  float2 mv = block_stats256(acc, sred);
  float y = (acc - mv.x) * rsqrtf(mv.y + 1e-5f) * g2[c] + bb2[c];
  y = y > 0.f ? y : (__expf(y) - 1.f);
  float pro2 = b2f(k2[((size_t)n*49 + s) * 256 + c]) + y;
  float2 mv2 = block_stats256(pro2, sred);
  float y2 = (pro2 - mv2.x) * rsqrtf(mv2.y + 1e-5f) * ng[c] + nb[c];
  obj0[(size_t)ns * 256 + c] = f2b(y2);
}

// ------------------------------------------------------------------
// gate at 7x7 (all NHWC): rec7 = k2 * sigmoid(obj)
// ------------------------------------------------------------------
__global__ __launch_bounds__(256) void gate7_k(
    const bf16* __restrict__ k2, const bf16* __restrict__ obj,
    bf16* __restrict__ rec7)
{
  size_t idx = (size_t)blockIdx.x * 256 + threadIdx.x;
  float ov = b2f(obj[idx]);
  rec7[idx] = f2b(b2f(k2[idx]) / (1.f + __expf(-ov)));
}

// ==================================================================
extern "C" void kernel_launch(void* const* d_in, const int* in_sizes, int n_in,
                              void* d_out, int out_size, void* d_ws, size_t ws_size,
                              hipStream_t stream)
{
  (void)hipGetLastError();  // clear stale errors

  static float h_sent[64];
  auto send_sentinel = [&](float val){
    for (int i = 0; i < 64; i++) h_sent[i] = val;
    hipMemcpyAsync(d_out, h_sent, 256, hipMemcpyHostToDevice, stream);
  };

  static const int EXP_SIZES[53] = {
    25690112, 32768, 100352, 1179648, 512, 512, 512, 196608, 768, 65536,
    256, 256, 256, 256, 256, 256, 256, 8388608, 32768, 64,
    64, 256, 256, 524288, 2048, 524288, 256, 589824, 2304, 196608,
    768, 768, 768, 768, 768, 1572864, 6144, 1572864, 768, 1179648,
    512, 512, 512, 1179648, 512, 512, 512, 1179648, 512, 589824,
    256, 256, 256 };
  if (n_in != 53){ send_sentinel(6600.f + (float)n_in); return; }
  for (int i = 0; i < 53; i++)
    if (in_sizes[i] != EXP_SIZES[i]){ send_sentinel(6000.f + 10.f*i); return; }
  if (out_size != 25690112){ send_sentinel(3000.f + (float)(out_size >> 20)); return; }
  if (ws_size < 77070400ull){ send_sentinel(2000.f + (float)(ws_size >> 20)); return; }

  const float* roi    = (const float*)d_in[0];
  const float* proF   = (const float*)d_in[1];
  const float* encW   = (const float*)d_in[3];
  const float* encB   = (const float*)d_in[4];
  const float* encG   = (const float*)d_in[5];
  const float* encBB  = (const float*)d_in[6];
  const float* aqkvW  = (const float*)d_in[7];
  const float* aqkvB  = (const float*)d_in[8];
  const float* aoutW  = (const float*)d_in[9];
  const float* aoutB  = (const float*)d_in[10];
  const float* n1g    = (const float*)d_in[11];
  const float* n1b    = (const float*)d_in[12];
  const float* n2g    = (const float*)d_in[13];
  const float* n2b    = (const float*)d_in[14];
  const float* n3g    = (const float*)d_in[15];
  const float* n3b    = (const float*)d_in[16];
  const float* dynW   = (const float*)d_in[17];
  const float* dynB   = (const float*)d_in[18];
  const float* dn1g   = (const float*)d_in[19];
  const float* dn1b   = (const float*)d_in[20];
  const float* dn2g   = (const float*)d_in[21];
  const float* dn2b   = (const float*)d_in[22];
  const float* lin1W  = (const float*)d_in[23];
  const float* lin1B  = (const float*)d_in[24];
  const float* lin2W  = (const float*)d_in[25];
  const float* lin2B  = (const float*)d_in[26];
  const float* teqkvW = (const float*)d_in[27];
  const float* teqkvB = (const float*)d_in[28];
  const float* teoutW = (const float*)d_in[29];
  const float* teoutB = (const float*)d_in[30];
  const float* teln1g = (const float*)d_in[31];
  const float* teln1b = (const float*)d_in[32];
  const float* teln2g = (const float*)d_in[33];
  const float* teln2b = (const float*)d_in[34];
  const float* teff1W = (const float*)d_in[35];
  const float* teff1B = (const float*)d_in[36];
  const float* teff2W = (const float*)d_in[37];
  const float* teff2B = (const float*)d_in[38];
  const float* recW   = (const float*)d_in[39];
  const float* recB   = (const float*)d_in[40];
  const float* recG   = (const float*)d_in[41];
  const float* recBB  = (const float*)d_in[42];
  const float* dAW    = (const float*)d_in[43];
  const float* dAB    = (const float*)d_in[44];
  const float* dAG    = (const float*)d_in[45];
  const float* dABB   = (const float*)d_in[46];
  const float* dBW    = (const float*)d_in[47];
  const float* dBB_   = (const float*)d_in[48];
  const float* dfW    = (const float*)d_in[49];
  const float* dfB    = (const float*)d_in[50];
  const float* dfG    = (const float*)d_in[51];
  const float* dfBB   = (const float*)d_in[52];

  // ---- workspace layout (bf16 elems). ws >= 77,070,400 bytes. ----
  bf16* base   = (bf16*)d_ws;
  bf16* wT     = base + 0;         //  5,308,416 (9 x 589,824), whole launch
  bf16* k1     = base + 5308416;   //  6,422,528  NHWC 14x14
  bf16* k2     = base + 11730944;  //  1,605,632  NHWC 7x7
  bf16* qkvP   = base + 13336576;  //     98,304
  bf16* attoP  = base + 13434880;  //     32,768
  bf16* mhaP   = base + 13467648;  //     32,768
  bf16* proQ   = base + 13500416;  //     32,768
  bf16* f1     = base + 13533184;  //    401,408
  bf16* obj0   = base + 13934592;  //  1,605,632
  bf16* tmp    = base + 15540224;  //  1,605,632
  bf16* atto   = base + 17145856;  //  1,605,632 (TE attn out; proB aliases early)
  bf16* obj    = base + 18751488;  //  1,605,632
  bf16* params = base + 20357120;  //  4,194,304 (dead after dyn_e2)
  bf16* rec7   = base + 20357120;  //  1,605,632 alias over params
  bf16* hbuf   = base + 24551424;  // 12,845,056 (FFN/TE only)
  bf16* qkvT   = base + 24551424;  //  4,816,896 alias over hbuf
  bf16* C14    = base + 24551424;  //  6,422,528 alias over hbuf
  bf16* B14    = base + 32112640;  //  6,422,528 (ends at byte 77,070,336)
  bf16* B28    = base + 5308416;   // 25,690,112 alias over k1..C14 (all dead)
  bf16* proB   = atto;             //     32,768 (dead before TE attn)
  // d_out (51,380,224 bf16 elems) as staged scratch, dead before final write:
  bf16* roiT   = (bf16*)d_out;             // [0 .. 25,690,112) bf16 NHWC roi
  bf16* C28    = (bf16*)d_out + 6422528;   // [6.4M .. 32.1M) (overwrites roiT tail late)
  bf16* gw     = (bf16*)d_out + 26214400;  // [26.2M .. 39.85M) bf16 GEMM weights
  bf16* A14    = (bf16*)d_out + 39845888;  // [39.85M .. 46.27M) keeps roiT alive
  bf16* gqkvW  = gw + 0;
  bf16* gaoutW = gw + 196608;
  bf16* gdynW  = gw + 262144;
  bf16* glin1W = gw + 8650752;
  bf16* glin2W = gw + 9175040;
  bf16* gteqkvW= gw + 9699328;
  bf16* gteoutW= gw + 10289152;
  bf16* gteff1W= gw + 10485760;
  bf16* gteff2W= gw + 12058624;
  float* score = (float*)((char*)d_ws + 77070336);  // 14-float scoreboard

  // ---- one-time layout transforms / dtype conversions ----
  auto cvt = [&](const float* s, bf16* d, int n){
    cvt_k<<<(n/4 + 255)/256, 256, 0, stream>>>(s, d, n/4);
  };
  troi_k<<<dim3(13,4,128),256,0,stream>>>(roi, roiT);
  wtrans_k<<<256,256,0,stream>>>(encW,            wT + 0*589824);
  wtrans_k<<<256,256,0,stream>>>(encW + 589824,   wT + 1*589824);
  wtrans_k<<<256,256,0,stream>>>(recW,            wT + 2*589824);
  wtrans_k<<<256,256,0,stream>>>(recW + 589824,   wT + 3*589824);
  wtrans_k<<<256,256,0,stream>>>(dAW,             wT + 4*589824);
  wtrans_k<<<256,256,0,stream>>>(dAW + 589824,    wT + 5*589824);
  wtrans_k<<<256,256,0,stream>>>(dBW,             wT + 6*589824);
  wtrans_k<<<256,256,0,stream>>>(dBW + 589824,    wT + 7*589824);
  wtrans_k<<<256,256,0,stream>>>(dfW,             wT + 8*589824);
  cvt(proF,   proB,    32768);
  cvt(aqkvW,  gqkvW,   196608);
  cvt(aoutW,  gaoutW,  65536);
  cvt(dynW,   gdynW,   8388608);
  cvt(lin1W,  glin1W,  524288);
  cvt(lin2W,  glin2W,  524288);
  cvt(teqkvW, gteqkvW, 589824);
  cvt(teoutW, gteoutW, 196608);
  cvt(teff1W, gteff1W, 1572864);
  cvt(teff2W, gteff2W, 1572864);
  probe_k<<<1,256,0,stream>>>(roiT, 25690112ull, score+0);

  // ---- k_encoder: 28 -> 14 -> 7 (NHWC) ----
  conv_mfma_k<14,14,28,28,0,2, 1,1,0,0,1,0><<<dim3(2,196),256,0,stream>>>(
      roiT, wT + 0*589824, encB, encG, encBB, nullptr, nullptr, k1);
  probe_k<<<1,256,0,stream>>>(k1, 6422528ull, score+1);
  conv_mfma_k<7,7,14,14,0,2, 1,1,0,0,1,0><<<dim3(2,49),256,0,stream>>>(
      k1, wT + 1*589824, encB+256, encG+256, encBB+256, nullptr, nullptr, k2);
  probe_k<<<1,256,0,stream>>>(k2, 1605632ull, score+2);

  // ---- self-attention over 128 query tokens ----
  gemm_mfma_k<0><<<dim3(6,1),256,0,stream>>>(proB, gqkvW, aqkvB, qkvP, 128,768,256);
  probe_k<<<1,256,0,stream>>>(qkvP, 98304ull, score+3);
  attn_k<128,8,32><<<dim3(8,2),64,0,stream>>>(qkvP, attoP);
  gemm_mfma_k<0><<<dim3(2,1),256,0,stream>>>(attoP, gaoutW, aoutB, mhaP, 128,256,256);
  add_ln_k<0,bf16><<<128,256,0,stream>>>(proB, mhaP, n1g, n1b, proQ);
  probe_k<<<1,256,0,stream>>>(proQ, 32768ull, score+4);

  // ---- DynamicConv ----
  gemm_mfma_k<0><<<dim3(256,1),256,0,stream>>>(proQ, gdynW, dynB, params, 128,32768,256);
  probe_k<<<1,256,0,stream>>>(params, 4194304ull, score+5);
  dyn_e1_k<<<128,256,0,stream>>>(k2, params, dn1g, dn1b, f1);
  probe_k<<<1,256,0,stream>>>(f1, 401408ull, score+6);
  dyn_e2_k<<<6272,256,0,stream>>>(k2, params, f1, dn2g, dn2b, n2g, n2b, obj0);
  probe_k<<<1,256,0,stream>>>(obj0, 1605632ull, score+7);

  // ---- FFN (ELU) + norm3 + PE ----
  gemm_mfma_k<2><<<dim3(16,49),256,0,stream>>>(obj0, glin1W, lin1B, hbuf, 6272,2048,256);
  gemm_mfma_k<0><<<dim3(2,49),256,0,stream>>>(hbuf, glin2W, lin2B, tmp, 6272,256,2048);
  add_ln_k<1,bf16><<<6272,256,0,stream>>>(obj0, tmp, n3g, n3b, obj);
  probe_k<<<1,256,0,stream>>>(obj, 1605632ull, score+8);

  // ---- 3-layer TransformerEncoder (post-norm, relu, nh=4) ----
  for (int l = 0; l < 3; l++){
    gemm_mfma_k<0><<<dim3(6,49),256,0,stream>>>(
        obj, gteqkvW + (size_t)l*196608, teqkvB + l*768, qkvT, 6272,768,256);
    attn_k<49,4,64><<<dim3(512,1),64,0,stream>>>(qkvT, atto);
    gemm_mfma_k<0><<<dim3(2,49),256,0,stream>>>(
        atto, gteoutW + (size_t)l*65536, teoutB + l*256, tmp, 6272,256,256);
    add_ln_k<0,bf16><<<6272,256,0,stream>>>(obj, tmp, teln1g + l*256, teln1b + l*256, obj);
    gemm_mfma_k<1><<<dim3(16,49),256,0,stream>>>(
        obj, gteff1W + (size_t)l*524288, teff1B + l*2048, hbuf, 6272,2048,256);
    gemm_mfma_k<0><<<dim3(2,49),256,0,stream>>>(
        hbuf, gteff2W + (size_t)l*524288, teff2B + l*256, tmp, 6272,256,2048);
    add_ln_k<0,bf16><<<6272,256,0,stream>>>(obj, tmp, teln2g + l*256, teln2b + l*256, obj);
  }
  probe_k<<<1,256,0,stream>>>(obj, 1605632ull, score+9);

  // ---- gated rec/det decoder pyramid (all NHWC) ----
  gate7_k<<<6272,256,0,stream>>>(k2, obj, rec7);
  probe_k<<<1,256,0,stream>>>(rec7, 1605632ull, score+10);
  // 7 -> 14
  conv_mfma_k<14,14,7,7,1,1, 1,1,1,0,1,0><<<dim3(2,196),256,0,stream>>>(
      rec7, wT + 2*589824, recB, recG, recBB, k1, nullptr, B14);
  probe_k<<<1,256,0,stream>>>(B14, 6422528ull, score+11);
  conv_mfma_k<14,14,7,7,1,1, 1,1,0,0,1,0><<<dim3(2,196),256,0,stream>>>(
      obj, wT + 4*589824, dAB, dAG, dABB, nullptr, nullptr, C14);
  conv_mfma_k<14,14,14,14,0,1, 0,0,1,1,1,0><<<dim3(2,196),256,0,stream>>>(
      C14, wT + 6*589824, dBB_, nullptr, nullptr, k1, B14, A14);
  probe_k<<<1,256,0,stream>>>(A14, 6422528ull, score+12);
  // 14 -> 28 (rec residual = bf16 NHWC roiT, still intact here)
  conv_mfma_k<28,28,14,14,1,1, 1,1,1,0,1,0><<<dim3(2,784),256,0,stream>>>(
      B14, wT + 3*589824, recB+256, recG+256, recBB+256, roiT, nullptr, B28);
  probe_k<<<1,256,0,stream>>>(B28, 25690112ull, score+13);
  conv_mfma_k<28,28,14,14,1,1, 1,1,0,0,1,0><<<dim3(2,784),256,0,stream>>>(
      A14, wT + 5*589824, dAB+256, dAG+256, dABB+256, nullptr, nullptr, C28);
  conv_mfma_k<28,28,28,28,0,1, 0,0,2,1,0,0><<<dim3(2,784),256,0,stream>>>(
      C28, wT + 7*589824, dBB_+256, nullptr, nullptr, roi, B28, nullptr);
  // final conv + BN + ReLU, FP32 NHWC into d_out
  conv_mfma_k<28,28,28,28,0,1, 1,1,0,0,1,1><<<dim3(2,784),256,0,stream>>>(
      B28, wT + 8*589824, dfB, dfG, dfBB, nullptr, nullptr, d_out);

  // ---- verdict + launch-error readout ----
  verdict_k<<<1,64,0,stream>>>(score, 14, (float*)d_out);
  hipError_t le = hipGetLastError();
  if (le != hipSuccess){
    float v = 7000.f + 16.f * (float)(int)le;
    if (v > 60000.f) v = 60000.f;
    send_sentinel(v);
  }
}

// Round 6
// 2030.027 us; speedup vs baseline: 1.4405x; 1.0782x over previous
//
#include <hip/hip_runtime.h>
#include <hip/hip_bf16.h>
#include <string.h>

typedef __hip_bfloat16 bf16;
typedef short bf16x8 __attribute__((ext_vector_type(8)));
typedef float f32x16 __attribute__((ext_vector_type(16)));

typedef __attribute__((address_space(3))) unsigned int       as3_u32;
typedef const __attribute__((address_space(1))) unsigned int as1_u32c;

__device__ __forceinline__ void dma16(const void* g, void* l){
  __builtin_amdgcn_global_load_lds((as1_u32c*)g, (as3_u32*)l, 16, 0, 0);
}

// zeros for conv padding rows (device globals are zero-initialized).
__device__ __align__(256) unsigned char g_zpad[1024];

__device__ __forceinline__ float b2f(bf16 v){ return __bfloat162float(v); }
__device__ __forceinline__ bf16  f2b(float v){ return __float2bfloat16(v); }
__device__ __forceinline__ unsigned short f2bu(float v){
  union { bf16 b; unsigned short u; } x; x.b = __float2bfloat16(v); return x.u;
}
__device__ __forceinline__ float ldf(const float* p, size_t i){ return p[i]; }
__device__ __forceinline__ float ldf(const bf16*  p, size_t i){ return b2f(p[i]); }

// bijective XCD-aware block remap (m204): chunk-contiguous per XCD
__device__ __forceinline__ int xcd_swizzle(int lin, int nwg){
  int q = nwg >> 3, r = nwg & 7;
  int x = lin & 7, i = lin >> 3;
  int base = (x < r) ? x * (q + 1) : r * (q + 1) + (x - r) * q;
  return base + i;
}

// ------------------------------------------------------------------
// block-wide (256 thr) mean/var helper. sred must be float[4] shared.
// ------------------------------------------------------------------
__device__ __forceinline__ float2 block_stats256(float x, float* sred){
  float v = x;
  #pragma unroll
  for (int o = 32; o; o >>= 1) v += __shfl_xor(v, o);
  int w = threadIdx.x >> 6;
  if ((threadIdx.x & 63) == 0) sred[w] = v;
  __syncthreads();
  float mean = (sred[0] + sred[1] + sred[2] + sred[3]) * (1.f/256.f);
  __syncthreads();
  float d = x - mean;
  v = d * d;
  #pragma unroll
  for (int o = 32; o; o >>= 1) v += __shfl_xor(v, o);
  if ((threadIdx.x & 63) == 0) sred[w] = v;
  __syncthreads();
  float var = (sred[0] + sred[1] + sred[2] + sred[3]) * (1.f/256.f);
  __syncthreads();
  return make_float2(mean, var);
}

// ---- diagnostics ----
__global__ __launch_bounds__(256) void probe_k(const bf16* __restrict__ buf,
                                               unsigned long long len, float* score){
  __shared__ float sred[4];
  unsigned long long stride = len / 256ull; if (!stride) stride = 1;
  unsigned long long i = (unsigned long long)threadIdx.x * stride;
  if (i >= len) i = len - 1;
  float v = fabsf(b2f(buf[i]));
  #pragma unroll
  for (int o = 32; o; o >>= 1) v = fmaxf(v, __shfl_xor(v, o));
  if ((threadIdx.x & 63) == 0) sred[threadIdx.x >> 6] = v;
  __syncthreads();
  if (threadIdx.x == 0)
    score[0] = fmaxf(fmaxf(sred[0], sred[1]), fmaxf(sred[2], sred[3]));
}

__global__ void verdict_k(const float* score, int nstage, float* out){
  if (threadIdx.x == 0 && blockIdx.x == 0){
    for (int i = 0; i < nstage; i++){
      float s = score[i];
      if (!(s > 1e-8f)){
        float sent = 1000.f + 40.f * i;
        for (int j = 0; j < 64; j++) out[j] = sent;
        return;
      }
    }
  }
}

// ------------------------------------------------------------------
// fp32 -> bf16 bulk convert (n/4 float4s)
// ------------------------------------------------------------------
__global__ __launch_bounds__(256) void cvt_k(const float* __restrict__ s,
                                             bf16* __restrict__ d, int n4){
  int i = blockIdx.x * 256 + threadIdx.x;
  if (i < n4){
    float4 f = reinterpret_cast<const float4*>(s)[i];
    ushort4 u;
    u.x = f2bu(f.x); u.y = f2bu(f.y); u.z = f2bu(f.z); u.w = f2bu(f.w);
    reinterpret_cast<ushort4*>(d)[i] = u;
  }
}

// ------------------------------------------------------------------
// transpose roi (fp32 NCHW 28x28) -> bf16 NHWC
// ------------------------------------------------------------------
__global__ __launch_bounds__(256) void troi_k(const float* __restrict__ roi,
                                              bf16* __restrict__ o){
  __shared__ float tile[64][65];
  int n = blockIdx.z, c0 = blockIdx.y * 64, p0 = blockIdx.x * 64;
  int a = threadIdx.x & 63, bq = threadIdx.x >> 6;
  #pragma unroll
  for (int cs = bq; cs < 64; cs += 4){
    int p = p0 + a;
    tile[cs][a] = (p < 784) ? roi[((size_t)n*256 + c0 + cs)*784 + p] : 0.f;
  }
  __syncthreads();
  #pragma unroll
  for (int ps = bq; ps < 64; ps += 4){
    int p = p0 + ps;
    if (p < 784) o[((size_t)n*784 + p)*256 + c0 + a] = f2b(tile[a][ps]);
  }
}

// ------------------------------------------------------------------
// weight transpose: w[co][ci][tap] fp32 -> wT[co][tap*256+ci] bf16
// ------------------------------------------------------------------
__global__ __launch_bounds__(256) void wtrans_k(const float* __restrict__ w,
                                                bf16* __restrict__ o){
  int co = blockIdx.x, t = threadIdx.x;
  const float* wp = w + (size_t)co * 2304 + (size_t)t * 9;
  #pragma unroll
  for (int tap = 0; tap < 9; tap++)
    o[(size_t)co * 2304 + tap * 256 + t] = f2b(wp[tap]);
}

// ------------------------------------------------------------------
// UP2 weight folding: for a conv applied to a 2x-nearest-upsampled
// image, the 9 taps at output parity (py,px) collapse onto a 2x2
// source window with pre-summed weights.
// w fp32 [co][ci][tap] -> wF bf16 [par][co][quad(2x2)][ci], K=1024.
// ------------------------------------------------------------------
__global__ __launch_bounds__(256) void wfold_k(const float* __restrict__ w,
                                               bf16* __restrict__ wF){
  int co = blockIdx.x, ci = threadIdx.x;
  float t9[9];
  #pragma unroll
  for (int k = 0; k < 9; k++) t9[k] = w[(size_t)co*2304 + (size_t)ci*9 + k];
  // mask[p][q]: which taps (bit d) feed quad q at parity p (per axis)
  const int msk[2][2] = {{0b001, 0b110}, {0b011, 0b100}};
  #pragma unroll
  for (int py = 0; py < 2; py++)
  #pragma unroll
  for (int px = 0; px < 2; px++){
    int par = py*2 + px;
    #pragma unroll
    for (int qy = 0; qy < 2; qy++)
    #pragma unroll
    for (int qx = 0; qx < 2; qx++){
      float s = 0.f;
      #pragma unroll
      for (int dy = 0; dy < 3; dy++) if ((msk[py][qy] >> dy) & 1)
        #pragma unroll
        for (int dx = 0; dx < 3; dx++) if ((msk[px][qx] >> dx) & 1)
          s += t9[dy*3 + dx];
      wF[(size_t)par*262144 + (size_t)co*1024 + (qy*2+qx)*256 + ci] = f2b(s);
    }
  }
}

// ------------------------------------------------------------------
// MFMA tile compute (128x128 block tile, 4 waves of 64x64, K-step 64)
// LDS row = 64 bf16 = 128B; 16B chunks XOR-permuted by ((row&7)<<4).
// DMA writes LDS LINEARLY; the permutation is applied on the per-lane
// GLOBAL source address at stage time, and again at read time.
// ------------------------------------------------------------------
__device__ __forceinline__ void mfma_step64(const unsigned short* As,
                                            const unsigned short* Bs,
                                            int wr, int wc, int lane,
                                            f32x16 (&acc)[2][2]){
  const char* asb = (const char*)As;
  const char* bsb = (const char*)Bs;
  int l31 = lane & 31;
  int lsw = (l31 & 7) << 4;
  int hi  = (lane >> 5) << 4;
  #pragma unroll
  for (int kb = 0; kb < 4; kb++){
    int cb = (kb*32 + hi) ^ lsw;
    bf16x8 a0 = *reinterpret_cast<const bf16x8*>(asb + (wr      + l31)*128 + cb);
    bf16x8 a1 = *reinterpret_cast<const bf16x8*>(asb + (wr + 32 + l31)*128 + cb);
    bf16x8 b0 = *reinterpret_cast<const bf16x8*>(bsb + (wc      + l31)*128 + cb);
    bf16x8 b1 = *reinterpret_cast<const bf16x8*>(bsb + (wc + 32 + l31)*128 + cb);
    acc[0][0] = __builtin_amdgcn_mfma_f32_32x32x16_bf16(a0, b0, acc[0][0], 0, 0, 0);
    acc[0][1] = __builtin_amdgcn_mfma_f32_32x32x16_bf16(a0, b1, acc[0][1], 0, 0, 0);
    acc[1][0] = __builtin_amdgcn_mfma_f32_32x32x16_bf16(a1, b0, acc[1][0], 0, 0, 0);
    acc[1][1] = __builtin_amdgcn_mfma_f32_32x32x16_bf16(a1, b1, acc[1][1], 0, 0, 0);
  }
}

// ------------------------------------------------------------------
// MFMA NT GEMM: C[M,N] = act(A[M,K] @ W[N,K]^T + bias), all bf16 in.
// M%128==0, N%128==0, K%64==0.
// DMA + LDS double-buffer, ONE barrier per K-step, placed AFTER the
// compute so prefetch DMAs overlap the MFMA phase.
// ------------------------------------------------------------------
template<int ACT>
__global__ __launch_bounds__(256) void gemm_mfma_k(
    const bf16* __restrict__ A, const bf16* __restrict__ W,
    const float* __restrict__ bias, bf16* __restrict__ C,
    int M, int N, int K)
{
  __shared__ __align__(16) unsigned short As[2][8192];
  __shared__ __align__(16) unsigned short Bs[2][8192];
  int t = threadIdx.x;
  int nbx = gridDim.x;
  int lin = blockIdx.y * nbx + blockIdx.x;
  int wg  = xcd_swizzle(lin, nbx * gridDim.y);
  int n0 = (wg % nbx) * 128, m0 = (wg / nbx) * 128;
  int lane = t & 63, wave = t >> 6;
  int wr = (wave >> 1) * 64, wc = (wave & 1) * 64;
  int lrow = lane >> 3;                         // 0..7: row within 8-row DMA group
  int e0   = (((lane & 7) ^ lrow) << 3);        // src element offset (inverse swizzle)

  f32x16 acc[2][2];
  #pragma unroll
  for (int i = 0; i < 2; i++)
    #pragma unroll
    for (int j = 0; j < 2; j++)
      #pragma unroll
      for (int r = 0; r < 16; r++) acc[i][j][r] = 0.f;

  const bf16* apr[4]; const bf16* bpr[4];
  #pragma unroll
  for (int i = 0; i < 4; i++){
    int r = wave*32 + i*8 + lrow;
    apr[i] = A + (size_t)(m0 + r) * K + e0;
    bpr[i] = W + (size_t)(n0 + r) * K + e0;
  }

  auto stage = [&](int buf, int k0){
    #pragma unroll
    for (int i = 0; i < 4; i++){
      dma16(apr[i] + k0, &As[buf][(wave*32 + i*8) * 64]);
      dma16(bpr[i] + k0, &Bs[buf][(wave*32 + i*8) * 64]);
    }
  };

  int NIT = K >> 6;
  stage(0, 0);
  __syncthreads();
  #pragma unroll 1
  for (int it = 0; it < NIT; ++it){
    if (it + 1 < NIT) stage((it+1)&1, (it+1)*64);   // issue early
    mfma_step64(As[it&1], Bs[it&1], wr, wc, lane, acc);
    __syncthreads();                               // wait late (drains prefetch)
  }

  int l31 = lane & 31;
  int rbase = m0 + wr + ((lane >> 5) << 2);
  #pragma unroll
  for (int j = 0; j < 2; j++){
    int n = n0 + wc + j*32 + l31;
    float bv = bias ? bias[n] : 0.f;
    #pragma unroll
    for (int i = 0; i < 2; i++){
      #pragma unroll
      for (int r = 0; r < 16; r++){
        int row = rbase + i*32 + (r & 3) + ((r >> 2) << 3);
        float v = acc[i][j][r] + bv;
        if (ACT == 1) v = fmaxf(v, 0.f);
        if (ACT == 2) v = v > 0.f ? v : (__expf(v) - 1.f);
        C[(size_t)row * N + n] = f2b(v);
      }
    }
  }
}

// ------------------------------------------------------------------
// MFMA 3x3 conv, Cin=Cout=256, pad 1, NHWC bf16 in/out, batch=128.
// Implicit GEMM: rows = (n*HWo+p), cols = co, K=2304 (36 steps of 64).
// DMA + LDS double-buffer, one barrier per K-step (issue-early/wait-late).
// RES_MODE: 0 none, 1 bf16 NHWC, 2 fp32 NCHW.
// ------------------------------------------------------------------
template<int Ho,int Wo,int Hi,int Wi,int UP2,int STRIDE,
         int HAS_BN,int RELU,int RES_MODE,int GATE,int WOUT,int OUTF>
__global__ __launch_bounds__(256) void conv_mfma_k(
    const bf16* __restrict__ in, const bf16* __restrict__ wTl,
    const float* __restrict__ cbias,
    const float* __restrict__ bng, const float* __restrict__ bnb,
    const void* __restrict__ res, bf16* __restrict__ gate,
    void* __restrict__ out)
{
  constexpr int HWo = Ho * Wo;
  constexpr int Hv = UP2 ? 2*Hi : Hi;
  constexpr int Wv = UP2 ? 2*Wi : Wi;
  __shared__ __align__(16) unsigned short As[2][8192];
  __shared__ __align__(16) unsigned short Bs[2][8192];
  int t = threadIdx.x;
  int nbx = gridDim.x;
  int lin = blockIdx.y * nbx + blockIdx.x;
  int wg  = xcd_swizzle(lin, nbx * gridDim.y);
  int co0 = (wg % nbx) * 128;
  int gp0 = (wg / nbx) * 128;
  int lane = t & 63, wave = t >> 6;
  int wr = (wave >> 1) * 64, wc = (wave & 1) * 64;
  int lrow = lane >> 3;
  int e0   = (((lane & 7) ^ lrow) << 3);

  // per-thread geometry of its 4 staged A-rows / B-rows
  int nA[4], oyA[4], oxA[4]; size_t wbase[4];
  #pragma unroll
  for (int i = 0; i < 4; i++){
    int r  = wave*32 + i*8 + lrow;
    int gp = gp0 + r;
    nA[i] = gp / HWo;
    int p = gp - nA[i] * HWo;
    oyA[i] = p / Wo; oxA[i] = p - oyA[i] * Wo;
    wbase[i] = (size_t)(co0 + r) * 2304 + e0;
  }

  f32x16 acc[2][2];
  #pragma unroll
  for (int i = 0; i < 2; i++)
    #pragma unroll
    for (int j = 0; j < 2; j++)
      #pragma unroll
      for (int r = 0; r < 16; r++) acc[i][j][r] = 0.f;

  const bf16* arp[4]; const bf16* brp[4];

  auto stage = [&](int buf, int it){
    int tap = it >> 2, sub = it & 3;
    if (sub == 0){
      int ky = tap / 3, kx = tap - ky * 3;
      #pragma unroll
      for (int i = 0; i < 4; i++){
        int iy = oyA[i]*STRIDE + ky - 1;
        int ix = oxA[i]*STRIDE + kx - 1;
        bool val = (iy >= 0) && (iy < Hv) && (ix >= 0) && (ix < Wv);
        int sy = UP2 ? (iy >> 1) : iy;
        int sx = UP2 ? (ix >> 1) : ix;
        arp[i] = val
          ? in + (((size_t)nA[i] * Hi + sy) * Wi + sx) * 256 + e0
          : (const bf16*)g_zpad + e0;
        brp[i] = wTl + wbase[i] + tap*256;
      }
    }
    #pragma unroll
    for (int i = 0; i < 4; i++){
      dma16(arp[i] + sub*64, &As[buf][(wave*32 + i*8) * 64]);
      dma16(brp[i] + sub*64, &Bs[buf][(wave*32 + i*8) * 64]);
    }
  };

  stage(0, 0);
  __syncthreads();
  #pragma unroll 1
  for (int it = 0; it < 36; ++it){
    if (it + 1 < 36) stage((it+1)&1, it+1);       // issue early
    mfma_step64(As[it&1], Bs[it&1], wr, wc, lane, acc);
    __syncthreads();                              // wait late
  }

  int l31 = lane & 31;
  int rbase = gp0 + wr + ((lane >> 5) << 2);
  #pragma unroll
  for (int j = 0; j < 2; j++){
    int co = co0 + wc + j*32 + l31;
    float cb = cbias[co];
    float scale = 1.f, shift = cb;
    if (HAS_BN){ float g = bng[co]; scale = g; shift = cb*g + bnb[co]; }
    #pragma unroll
    for (int i = 0; i < 2; i++){
      #pragma unroll
      for (int r = 0; r < 16; r++){
        int grow = rbase + i*32 + (r & 3) + ((r >> 2) << 3);
        float v = acc[i][j][r] * scale + shift;
        if (RELU) v = fmaxf(v, 0.f);
        size_t oidx = (size_t)grow * 256 + co;
        if (RES_MODE == 1) v += b2f(((const bf16*)res)[oidx]);
        if (RES_MODE == 2){
          int rn = grow / HWo, rp = grow - rn * HWo;
          v += ((const float*)res)[((size_t)rn * 256 + co) * HWo + rp];
        }
        if (GATE){
          float gv = b2f(gate[oidx]);
          gate[oidx] = f2b(gv / (1.f + __expf(-v)));
        }
        if (WOUT){
          if (OUTF) ((float*)out)[oidx] = v;
          else      ((bf16*)out)[oidx]  = f2b(v);
        }
      }
    }
  }
}

// ------------------------------------------------------------------
// Folded UP2 3x3 conv (2x-nearest-upsample + conv3x3 pad1), K=1024.
// Each block handles 128 output positions of ONE parity (py,px).
// Rows: per-parity index gp -> (n, ty, tx); output (2ty+py, 2tx+px).
// K layout: [quad(2x2 src window)][ci 256] -> 16 K-steps of 64.
// RES: 0 none, 1 bf16 NHWC residual.
// ------------------------------------------------------------------
template<int Ho,int Wo,int Hi,int Wi,int RES>
__global__ __launch_bounds__(256) void convup_k(
    const bf16* __restrict__ in, const bf16* __restrict__ wF,
    const float* __restrict__ cbias,
    const float* __restrict__ bng, const float* __restrict__ bnb,
    const bf16* __restrict__ res, bf16* __restrict__ out)
{
  constexpr int Ty = Ho/2, Tx = Wo/2;
  constexpr int HWt = Ty * Tx;                  // tiles per image per parity
  __shared__ __align__(16) unsigned short As[2][8192];
  __shared__ __align__(16) unsigned short Bs[2][8192];
  int t = threadIdx.x;
  int nbx = gridDim.x;
  int lin = blockIdx.y * nbx + blockIdx.x;
  int wg  = xcd_swizzle(lin, nbx * gridDim.y);
  int co0 = (wg % nbx) * 128;
  int gb  = wg / nbx;                           // [0, 4*HWt)
  int par = gb / HWt;
  int gp0 = (gb - par * HWt) * 128;
  int py = par >> 1, px = par & 1;
  int oyOff = py ? 0 : 1, oxOff = px ? 0 : 1;
  int lane = t & 63, wave = t >> 6;
  int wr = (wave >> 1) * 64, wc = (wave & 1) * 64;
  int lrow = lane >> 3;
  int e0   = (((lane & 7) ^ lrow) << 3);

  int nA[4], tyA[4], txA[4]; const bf16* brp[4];
  #pragma unroll
  for (int i = 0; i < 4; i++){
    int r  = wave*32 + i*8 + lrow;
    int gp = gp0 + r;
    nA[i] = gp / HWt;
    int tp = gp - nA[i] * HWt;
    tyA[i] = tp / Tx; txA[i] = tp - tyA[i] * Tx;
    brp[i] = wF + (size_t)par*262144 + (size_t)(co0 + r)*1024 + e0;
  }

  f32x16 acc[2][2];
  #pragma unroll
  for (int i = 0; i < 2; i++)
    #pragma unroll
    for (int j = 0; j < 2; j++)
      #pragma unroll
      for (int r = 0; r < 16; r++) acc[i][j][r] = 0.f;

  const bf16* arp[4];
  auto stage = [&](int buf, int it){
    int quad = it >> 2, sub = it & 3;
    if (sub == 0){
      int qy = quad >> 1, qx = quad & 1;
      #pragma unroll
      for (int i = 0; i < 4; i++){
        int sy = tyA[i] + qy - oyOff;
        int sx = txA[i] + qx - oxOff;
        bool val = (sy >= 0) && (sy < Hi) && (sx >= 0) && (sx < Wi);
        arp[i] = val
          ? in + (((size_t)nA[i] * Hi + sy) * Wi + sx) * 256 + e0
          : (const bf16*)g_zpad + e0;
      }
    }
    #pragma unroll
    for (int i = 0; i < 4; i++){
      dma16(arp[i] + sub*64, &As[buf][(wave*32 + i*8) * 64]);
      dma16(brp[i] + it*64,  &Bs[buf][(wave*32 + i*8) * 64]);
    }
  };

  stage(0, 0);
  __syncthreads();
  #pragma unroll 1
  for (int it = 0; it < 16; ++it){
    if (it + 1 < 16) stage((it+1)&1, it+1);       // issue early
    mfma_step64(As[it&1], Bs[it&1], wr, wc, lane, acc);
    __syncthreads();                              // wait late
  }

  int l31 = lane & 31;
  int rbase = gp0 + wr + ((lane >> 5) << 2);
  #pragma unroll
  for (int j = 0; j < 2; j++){
    int co = co0 + wc + j*32 + l31;
    float cb = cbias[co];
    float scale = 1.f, shift = cb;
    float g = bng[co]; scale = g; shift = cb*g + bnb[co];
    #pragma unroll
    for (int i = 0; i < 2; i++){
      #pragma unroll
      for (int r = 0; r < 16; r++){
        int grow = rbase + i*32 + (r & 3) + ((r >> 2) << 3);
        int n  = grow / HWt;
        int tp = grow - n * HWt;
        int ty = tp / Tx, tx = tp - ty * Tx;
        int oy = 2*ty + py, ox = 2*tx + px;
        size_t oidx = (((size_t)n * Ho + oy) * Wo + ox) * 256 + co;
        float v = acc[i][j][r] * scale + shift;
        v = fmaxf(v, 0.f);
        if (RES == 1) v += b2f(res[oidx]);
        out[oidx] = f2b(v);
      }
    }
  }
}

// ------------------------------------------------------------------
// MHA (online softmax). qkv rows (b*S+s), cols [q|k|v] each D=NH*DH.
// ------------------------------------------------------------------
template<int S, int NH, int DH>
__global__ __launch_bounds__(64) void attn_k(
    const bf16* __restrict__ qkv, bf16* __restrict__ out)
{
  const int D = NH * DH;
  int b = blockIdx.x / NH, h = blockIdx.x % NH;
  int chunk = blockIdx.y;
  int lane = threadIdx.x;
  __shared__ float ks[S][DH];
  __shared__ float vs[S][DH];
  __shared__ float os[64][DH];
  for (int idx = lane; idx < S*DH; idx += 64){
    int tt = idx / DH, d = idx % DH;
    size_t row = (size_t)(b*S + tt) * (3*D);
    ks[tt][d] = b2f(qkv[row +   D + h*DH + d]);
    vs[tt][d] = b2f(qkv[row + 2*D + h*DH + d]);
  }
  __syncthreads();
  int s = chunk*64 + lane;
  float q[DH];
  const float scale = 1.f / sqrtf((float)DH);
  if (s < S){
    size_t row = (size_t)(b*S + s) * (3*D);
    #pragma unroll
    for (int d = 0; d < DH; d++) q[d] = b2f(qkv[row + h*DH + d]) * scale;
  } else {
    #pragma unroll
    for (int d = 0; d < DH; d++) q[d] = 0.f;
  }
  float o[DH];
  #pragma unroll
  for (int d = 0; d < DH; d++) o[d] = 0.f;
  float m = -1e30f, l = 0.f;
  for (int tt = 0; tt < S; tt++){
    float sc = 0.f;
    #pragma unroll
    for (int d = 0; d < DH; d++) sc = fmaf(q[d], ks[tt][d], sc);
    float mn = fmaxf(m, sc);
    float corr = __expf(m - mn);
    float e = __expf(sc - mn);
    l = l * corr + e;
    #pragma unroll
    for (int d = 0; d < DH; d++) o[d] = fmaf(o[d], corr, e * vs[tt][d]);
    m = mn;
  }
  float inv = 1.f / l;
  #pragma unroll
  for (int d = 0; d < DH; d++) os[lane][d] = o[d] * inv;
  __syncthreads();
  for (int idx = lane; idx < 64*DH; idx += 64){
    int sl = idx / DH, d = idx % DH;
    int ss = chunk*64 + sl;
    if (ss < S) out[(size_t)(b*S + ss) * D + h*DH + d] = f2b(os[sl][d]);
  }
}

// ------------------------------------------------------------------
// out[r,:] = LN(a[r,:]+b[r,:]) * g + bb  (+ PE[r%49,:] if ADD_PE)
// ------------------------------------------------------------------
template<int ADD_PE, typename TA>
__global__ __launch_bounds__(256) void add_ln_k(
    const TA* __restrict__ a, const bf16* __restrict__ bsrc,
    const float* __restrict__ g, const float* __restrict__ bb, bf16* out)
{
  __shared__ float sred[4];
  int r = blockIdx.x, c = threadIdx.x;
  size_t idx = (size_t)r * 256 + c;
  float x = ldf(a, idx) + b2f(bsrc[idx]);
  float2 mv = block_stats256(x, sred);
  float y = (x - mv.x) * rsqrtf(mv.y + 1e-5f) * g[c] + bb[c];
  if (ADD_PE){
    int s = r % 49;
    float freq = __expf((float)(c & ~1) * (-9.210340371976184f / 256.f));
    float ang = (float)s * freq;
    y += (c & 1) ? cosf(ang) : sinf(ang);
  }
  out[idx] = f2b(y);
}

// ------------------------------------------------------------------
// DynamicConv stage 1: f1[n,s,d] = elu(LN_d(sum_c feats[n,s,c]*p1[n,c,d]))
// ------------------------------------------------------------------
__global__ __launch_bounds__(256) void dyn_e1_k(
    const bf16* __restrict__ k2, const bf16* __restrict__ params,
    const float* __restrict__ g, const float* __restrict__ bb,
    bf16* __restrict__ f1)
{
  int n = blockIdx.x;
  int w = threadIdx.x >> 6, d = threadIdx.x & 63;
  const bf16* pp = params + (size_t)n * 32768 + d;
  for (int s = w; s < 49; s += 4){
    const bf16* fp = k2 + ((size_t)n*49 + s) * 256;
    float acc = 0.f;
    #pragma unroll 4
    for (int c = 0; c < 256; c++)
      acc = fmaf(b2f(fp[c]), b2f(pp[c*64]), acc);
    float v = acc;
    #pragma unroll
    for (int o = 32; o; o >>= 1) v += __shfl_xor(v, o);
    float mean = v * (1.f/64.f);
    float dd = acc - mean;
    v = dd * dd;
    #pragma unroll
    for (int o = 32; o; o >>= 1) v += __shfl_xor(v, o);
    float var = v * (1.f/64.f);
    float y = dd * rsqrtf(var + 1e-5f) * g[d] + bb[d];
    y = y > 0.f ? y : (__expf(y) - 1.f);
    f1[((size_t)n*49 + s) * 64 + d] = f2b(y);
  }
}

// ------------------------------------------------------------------
// DynamicConv stage 2 + norm2 (k2 NHWC)
// ------------------------------------------------------------------
__global__ __launch_bounds__(256) void dyn_e2_k(
    const bf16* __restrict__ k2, const bf16* __restrict__ params,
    const bf16* __restrict__ f1,
    const float* __restrict__ g2, const float* __restrict__ bb2,
    const float* __restrict__ ng, const float* __restrict__ nb,
    bf16* __restrict__ obj0)
{
  __shared__ float sred[4];
  int ns = blockIdx.x; int n = ns / 49, s = ns % 49;
  int c = threadIdx.x;
  const bf16* pp  = params + (size_t)n * 32768 + 16384 + c;
  const bf16* f1p = f1 + (size_t)ns * 64;
  float acc = 0.f;
  #pragma unroll 8
  for (int d = 0; d < 64; d++)
    acc = fmaf(b2f(f1p[d]), b2f(pp[d*256]), acc);
  float2 mv = block_stats256(acc, sred);
  float y = (acc - mv.x) * rsqrtf(mv.y + 1e-5f) * g2[c] + bb2[c];
  y = y > 0.f ? y : (__expf(y) - 1.f);
  float pro2 = b2f(k2[((size_t)n*49 + s) * 256 + c]) + y;
  float2 mv2 = block_stats256(pro2, sred);
  float y2 = (pro2 - mv2.x) * rsqrtf(mv2.y + 1e-5f) * ng[c] + nb[c];
  obj0[(size_t)ns * 256 + c] = f2b(y2);
}

// ------------------------------------------------------------------
// gate at 7x7 (all NHWC): rec7 = k2 * sigmoid(obj)
// ------------------------------------------------------------------
__global__ __launch_bounds__(256) void gate7_k(
    const bf16* __restrict__ k2, const bf16* __restrict__ obj,
    bf16* __restrict__ rec7)
{
  size_t idx = (size_t)blockIdx.x * 256 + threadIdx.x;
  float ov = b2f(obj[idx]);
  rec7[idx] = f2b(b2f(k2[idx]) / (1.f + __expf(-ov)));
}

// ==================================================================
extern "C" void kernel_launch(void* const* d_in, const int* in_sizes, int n_in,
                              void* d_out, int out_size, void* d_ws, size_t ws_size,
                              hipStream_t stream)
{
  (void)hipGetLastError();  // clear stale errors

  static float h_sent[64];
  auto send_sentinel = [&](float val){
    for (int i = 0; i < 64; i++) h_sent[i] = val;
    hipMemcpyAsync(d_out, h_sent, 256, hipMemcpyHostToDevice, stream);
  };

  static const int EXP_SIZES[53] = {
    25690112, 32768, 100352, 1179648, 512, 512, 512, 196608, 768, 65536,
    256, 256, 256, 256, 256, 256, 256, 8388608, 32768, 64,
    64, 256, 256, 524288, 2048, 524288, 256, 589824, 2304, 196608,
    768, 768, 768, 768, 768, 1572864, 6144, 1572864, 768, 1179648,
    512, 512, 512, 1179648, 512, 512, 512, 1179648, 512, 589824,
    256, 256, 256 };
  if (n_in != 53){ send_sentinel(6600.f + (float)n_in); return; }
  for (int i = 0; i < 53; i++)
    if (in_sizes[i] != EXP_SIZES[i]){ send_sentinel(6000.f + 10.f*i); return; }
  if (out_size != 25690112){ send_sentinel(3000.f + (float)(out_size >> 20)); return; }
  if (ws_size < 77070400ull){ send_sentinel(2000.f + (float)(ws_size >> 20)); return; }

  const float* roi    = (const float*)d_in[0];
  const float* proF   = (const float*)d_in[1];
  const float* encW   = (const float*)d_in[3];
  const float* encB   = (const float*)d_in[4];
  const float* encG   = (const float*)d_in[5];
  const float* encBB  = (const float*)d_in[6];
  const float* aqkvW  = (const float*)d_in[7];
  const float* aqkvB  = (const float*)d_in[8];
  const float* aoutW  = (const float*)d_in[9];
  const float* aoutB  = (const float*)d_in[10];
  const float* n1g    = (const float*)d_in[11];
  const float* n1b    = (const float*)d_in[12];
  const float* n2g    = (const float*)d_in[13];
  const float* n2b    = (const float*)d_in[14];
  const float* n3g    = (const float*)d_in[15];
  const float* n3b    = (const float*)d_in[16];
  const float* dynW   = (const float*)d_in[17];
  const float* dynB   = (const float*)d_in[18];
  const float* dn1g   = (const float*)d_in[19];
  const float* dn1b   = (const float*)d_in[20];
  const float* dn2g   = (const float*)d_in[21];
  const float* dn2b   = (const float*)d_in[22];
  const float* lin1W  = (const float*)d_in[23];
  const float* lin1B  = (const float*)d_in[24];
  const float* lin2W  = (const float*)d_in[25];
  const float* lin2B  = (const float*)d_in[26];
  const float* teqkvW = (const float*)d_in[27];
  const float* teqkvB = (const float*)d_in[28];
  const float* teoutW = (const float*)d_in[29];
  const float* teoutB = (const float*)d_in[30];
  const float* teln1g = (const float*)d_in[31];
  const float* teln1b = (const float*)d_in[32];
  const float* teln2g = (const float*)d_in[33];
  const float* teln2b = (const float*)d_in[34];
  const float* teff1W = (const float*)d_in[35];
  const float* teff1B = (const float*)d_in[36];
  const float* teff2W = (const float*)d_in[37];
  const float* teff2B = (const float*)d_in[38];
  const float* recW   = (const float*)d_in[39];
  const float* recB   = (const float*)d_in[40];
  const float* recG   = (const float*)d_in[41];
  const float* recBB  = (const float*)d_in[42];
  const float* dAW    = (const float*)d_in[43];
  const float* dAB    = (const float*)d_in[44];
  const float* dAG    = (const float*)d_in[45];
  const float* dABB   = (const float*)d_in[46];
  const float* dBW    = (const float*)d_in[47];
  const float* dBB_   = (const float*)d_in[48];
  const float* dfW    = (const float*)d_in[49];
  const float* dfB    = (const float*)d_in[50];
  const float* dfG    = (const float*)d_in[51];
  const float* dfBB   = (const float*)d_in[52];

  // ---- workspace layout (bf16 elems). ws >= 77,070,400 bytes. ----
  bf16* base   = (bf16*)d_ws;
  bf16* wT     = base + 0;         //  5,308,416 (9 slots; 2..5 unused now)
  bf16* k1     = base + 5308416;   //  6,422,528  NHWC 14x14
  bf16* k2     = base + 11730944;  //  1,605,632  NHWC 7x7
  bf16* qkvP   = base + 13336576;  //     98,304
  bf16* attoP  = base + 13434880;  //     32,768
  bf16* mhaP   = base + 13467648;  //     32,768
  bf16* proQ   = base + 13500416;  //     32,768
  bf16* f1     = base + 13533184;  //    401,408
  bf16* obj0   = base + 13934592;  //  1,605,632
  bf16* tmp    = base + 15540224;  //  1,605,632
  bf16* atto   = base + 17145856;  //  1,605,632 (TE attn out; proB aliases early)
  bf16* obj    = base + 18751488;  //  1,605,632
  bf16* params = base + 20357120;  //  4,194,304 (dead after dyn_e2)
  bf16* rec7   = base + 20357120;  //  1,605,632 alias over params
  bf16* hbuf   = base + 24551424;  // 12,845,056 (FFN/TE only)
  bf16* qkvT   = base + 24551424;  //  4,816,896 alias over hbuf
  bf16* C14    = base + 24551424;  //  6,422,528 alias over hbuf
  bf16* B14    = base + 32112640;  //  6,422,528 (ends at byte 77,070,336)
  bf16* B28    = base + 5308416;   // 25,690,112 alias over k1..C14 (all dead)
  bf16* proB   = atto;             //     32,768 (dead before TE attn)
  // d_out (51,380,224 bf16 elems) as staged scratch, dead before final write:
  bf16* roiT   = (bf16*)d_out;             // [0 .. 25,690,112) bf16 NHWC roi
  bf16* C28    = (bf16*)d_out + 6422528;   // [6.4M .. 32.1M) (overwrites roiT tail late)
  bf16* gw     = (bf16*)d_out + 26214400;  // [26.2M .. 39.85M) bf16 GEMM weights
  bf16* A14    = (bf16*)d_out + 39845888;  // [39.85M .. 46.27M)
  bf16* wFrec1 = (bf16*)d_out + 46268416;  // 1,048,576 folded UP2 weights (7->14 rec)
  bf16* wFrec2 = wFrec1 + 1048576;         // (14->28 rec)
  bf16* wFdA1  = wFrec1 + 2097152;         // (7->14 det)
  bf16* wFdA2  = wFrec1 + 3145728;         // (14->28 det); ends 50,462,720
  bf16* gqkvW  = gw + 0;
  bf16* gaoutW = gw + 196608;
  bf16* gdynW  = gw + 262144;
  bf16* glin1W = gw + 8650752;
  bf16* glin2W = gw + 9175040;
  bf16* gteqkvW= gw + 9699328;
  bf16* gteoutW= gw + 10289152;
  bf16* gteff1W= gw + 10485760;
  bf16* gteff2W= gw + 12058624;
  float* score = (float*)((char*)d_ws + 77070336);  // 14-float scoreboard

  // ---- one-time layout transforms / dtype conversions ----
  auto cvt = [&](const float* s, bf16* d, int n){
    cvt_k<<<(n/4 + 255)/256, 256, 0, stream>>>(s, d, n/4);
  };
  troi_k<<<dim3(13,4,128),256,0,stream>>>(roi, roiT);
  wtrans_k<<<256,256,0,stream>>>(encW,            wT + 0*589824);
  wtrans_k<<<256,256,0,stream>>>(encW + 589824,   wT + 1*589824);
  wtrans_k<<<256,256,0,stream>>>(dBW,             wT + 6*589824);
  wtrans_k<<<256,256,0,stream>>>(dBW + 589824,    wT + 7*589824);
  wtrans_k<<<256,256,0,stream>>>(dfW,             wT + 8*589824);
  wfold_k<<<256,256,0,stream>>>(recW,           wFrec1);
  wfold_k<<<256,256,0,stream>>>(recW + 589824,  wFrec2);
  wfold_k<<<256,256,0,stream>>>(dAW,            wFdA1);
  wfold_k<<<256,256,0,stream>>>(dAW + 589824,   wFdA2);
  cvt(proF,   proB,    32768);
  cvt(aqkvW,  gqkvW,   196608);
  cvt(aoutW,  gaoutW,  65536);
  cvt(dynW,   gdynW,   8388608);
  cvt(lin1W,  glin1W,  524288);
  cvt(lin2W,  glin2W,  524288);
  cvt(teqkvW, gteqkvW, 589824);
  cvt(teoutW, gteoutW, 196608);
  cvt(teff1W, gteff1W, 1572864);
  cvt(teff2W, gteff2W, 1572864);
  probe_k<<<1,256,0,stream>>>(roiT, 25690112ull, score+0);

  // ---- k_encoder: 28 -> 14 -> 7 (NHWC) ----
  conv_mfma_k<14,14,28,28,0,2, 1,1,0,0,1,0><<<dim3(2,196),256,0,stream>>>(
      roiT, wT + 0*589824, encB, encG, encBB, nullptr, nullptr, k1);
  probe_k<<<1,256,0,stream>>>(k1, 6422528ull, score+1);
  conv_mfma_k<7,7,14,14,0,2, 1,1,0,0,1,0><<<dim3(2,49),256,0,stream>>>(
      k1, wT + 1*589824, encB+256, encG+256, encBB+256, nullptr, nullptr, k2);
  probe_k<<<1,256,0,stream>>>(k2, 1605632ull, score+2);

  // ---- self-attention over 128 query tokens ----
  gemm_mfma_k<0><<<dim3(6,1),256,0,stream>>>(proB, gqkvW, aqkvB, qkvP, 128,768,256);
  probe_k<<<1,256,0,stream>>>(qkvP, 98304ull, score+3);
  attn_k<128,8,32><<<dim3(8,2),64,0,stream>>>(qkvP, attoP);
  gemm_mfma_k<0><<<dim3(2,1),256,0,stream>>>(attoP, gaoutW, aoutB, mhaP, 128,256,256);
  add_ln_k<0,bf16><<<128,256,0,stream>>>(proB, mhaP, n1g, n1b, proQ);
  probe_k<<<1,256,0,stream>>>(proQ, 32768ull, score+4);

  // ---- DynamicConv ----
  gemm_mfma_k<0><<<dim3(256,1),256,0,stream>>>(proQ, gdynW, dynB, params, 128,32768,256);
  probe_k<<<1,256,0,stream>>>(params, 4194304ull, score+5);
  dyn_e1_k<<<128,256,0,stream>>>(k2, params, dn1g, dn1b, f1);
  probe_k<<<1,256,0,stream>>>(f1, 401408ull, score+6);
  dyn_e2_k<<<6272,256,0,stream>>>(k2, params, f1, dn2g, dn2b, n2g, n2b, obj0);
  probe_k<<<1,256,0,stream>>>(obj0, 1605632ull, score+7);

  // ---- FFN (ELU) + norm3 + PE ----
  gemm_mfma_k<2><<<dim3(16,49),256,0,stream>>>(obj0, glin1W, lin1B, hbuf, 6272,2048,256);
  gemm_mfma_k<0><<<dim3(2,49),256,0,stream>>>(hbuf, glin2W, lin2B, tmp, 6272,256,2048);
  add_ln_k<1,bf16><<<6272,256,0,stream>>>(obj0, tmp, n3g, n3b, obj);
  probe_k<<<1,256,0,stream>>>(obj, 1605632ull, score+8);

  // ---- 3-layer TransformerEncoder (post-norm, relu, nh=4) ----
  for (int l = 0; l < 3; l++){
    gemm_mfma_k<0><<<dim3(6,49),256,0,stream>>>(
        obj, gteqkvW + (size_t)l*196608, teqkvB + l*768, qkvT, 6272,768,256);
    attn_k<49,4,64><<<dim3(512,1),64,0,stream>>>(qkvT, atto);
    gemm_mfma_k<0><<<dim3(2,49),256,0,stream>>>(
        atto, gteoutW + (size_t)l*65536, teoutB + l*256, tmp, 6272,256,256);
    add_ln_k<0,bf16><<<6272,256,0,stream>>>(obj, tmp, teln1g + l*256, teln1b + l*256, obj);
    gemm_mfma_k<1><<<dim3(16,49),256,0,stream>>>(
        obj, gteff1W + (size_t)l*524288, teff1B + l*2048, hbuf, 6272,2048,256);
    gemm_mfma_k<0><<<dim3(2,49),256,0,stream>>>(
        hbuf, gteff2W + (size_t)l*524288, teff2B + l*256, tmp, 6272,256,2048);
    add_ln_k<0,bf16><<<6272,256,0,stream>>>(obj, tmp, teln2g + l*256, teln2b + l*256, obj);
  }
  probe_k<<<1,256,0,stream>>>(obj, 1605632ull, score+9);

  // ---- gated rec/det decoder pyramid (all NHWC) ----
  gate7_k<<<6272,256,0,stream>>>(k2, obj, rec7);
  probe_k<<<1,256,0,stream>>>(rec7, 1605632ull, score+10);
  // 7 -> 14 (folded UP2, K=1024)
  convup_k<14,14,7,7, 1><<<dim3(2,196),256,0,stream>>>(
      rec7, wFrec1, recB, recG, recBB, k1, B14);
  probe_k<<<1,256,0,stream>>>(B14, 6422528ull, score+11);
  convup_k<14,14,7,7, 0><<<dim3(2,196),256,0,stream>>>(
      obj, wFdA1, dAB, dAG, dABB, nullptr, C14);
  conv_mfma_k<14,14,14,14,0,1, 0,0,1,1,1,0><<<dim3(2,196),256,0,stream>>>(
      C14, wT + 6*589824, dBB_, nullptr, nullptr, k1, B14, A14);
  probe_k<<<1,256,0,stream>>>(A14, 6422528ull, score+12);
  // 14 -> 28 (folded UP2, K=1024; rec residual = bf16 NHWC roiT)
  convup_k<28,28,14,14, 1><<<dim3(2,784),256,0,stream>>>(
      B14, wFrec2, recB+256, recG+256, recBB+256, roiT, B28);
  probe_k<<<1,256,0,stream>>>(B28, 25690112ull, score+13);
  convup_k<28,28,14,14, 0><<<dim3(2,784),256,0,stream>>>(
      A14, wFdA2, dAB+256, dAG+256, dABB+256, nullptr, C28);
  conv_mfma_k<28,28,28,28,0,1, 0,0,2,1,0,0><<<dim3(2,784),256,0,stream>>>(
      C28, wT + 7*589824, dBB_+256, nullptr, nullptr, roi, B28, nullptr);
  // final conv + BN + ReLU, FP32 NHWC into d_out
  conv_mfma_k<28,28,28,28,0,1, 1,1,0,0,1,1><<<dim3(2,784),256,0,stream>>>(
      B28, wT + 8*589824, dfB, dfG, dfBB, nullptr, nullptr, d_out);

  // ---- verdict + launch-error readout ----
  verdict_k<<<1,64,0,stream>>>(score, 14, (float*)d_out);
  hipError_t le = hipGetLastError();
  if (le != hipSuccess){
    float v = 7000.f + 16.f * (float)(int)le;
    if (v > 60000.f) v = 60000.f;
    send_sentinel(v);
  }
}